// Round 8
// baseline (954.440 us; speedup 1.0000x reference)
//
#include <hip/hip_runtime.h>

#define DT_F 0.01f
#define EPS_F 1e-5f
#define NEG_INF_I (-1073741824)

typedef _Float16 f16;
typedef _Float16 f16x2 __attribute__((ext_vector_type(2)));

__device__ __forceinline__ float rl(float v, int l) {
  return __int_as_float(__builtin_amdgcn_readlane(__float_as_int(v), l));
}
__device__ __forceinline__ float sigm(float x) { return 1.0f / (1.0f + __expf(-x)); }
__device__ __forceinline__ float tanhf_fast(float x) {
  float e = __expf(-2.0f * fabsf(x));
  float t = (1.0f - e) / (1.0f + e);
  return x < 0.0f ? -t : t;
}
__device__ __forceinline__ float dot2(unsigned w, unsigned h, float acc) {
  return __builtin_amdgcn_fdot2(__builtin_bit_cast(f16x2, w),
                                __builtin_bit_cast(f16x2, h), acc, false);
}
__device__ __forceinline__ unsigned packf16(float a, float b) {
  return __builtin_bit_cast(unsigned, __builtin_amdgcn_cvt_pkrtz(a, b));
}
// residency anchor: opaque def — cannot be rematerialized as a load
#define ANCH4(v) asm volatile("" : "+v"((v).x), "+v"((v).y), "+v"((v).z), "+v"((v).w))
#define ANCHF(v) asm volatile("" : "+v"(v))

// evtab[k*B + sid] = (last obs index in event k's window with sample_ids==sid) + 1, or 0.
__global__ void build_evtab_kernel(const int* __restrict__ sample_ids,
                                   const int* __restrict__ time_ptr,
                                   int* __restrict__ evtab, int B, int ope) {
  int k = blockIdx.x;
  int base = time_ptr[k];
  for (int t = threadIdx.x; t < ope; t += blockDim.x) {
    int obs = base + t;
    int sid = sample_ids[obs];
    atomicMax(&evtab[k * B + sid], obs + 1);   // last occurrence wins
  }
}

// Pack weight rows into f16-pair (u32) form (verified R7):
//  odeP/bayP: [3][64][32] pairs; wihP: [3][64][4] pairs (IN<=8, zero-padded)
__global__ void pack_pairs_kernel(const float* __restrict__ ghr,
                                  const float* __restrict__ ghz,
                                  const float* __restrict__ ghh,
                                  const float* __restrict__ gbWhh,
                                  const float* __restrict__ gbWih,
                                  unsigned* __restrict__ odeP,
                                  unsigned* __restrict__ bayP,
                                  unsigned* __restrict__ wihP, int IN) {
  int idx = blockIdx.x * 256 + threadIdx.x;
  if (idx < 3 * 64 * 32) {
    int p = idx & 31, r = idx >> 5;
    int g = r >> 6, i = r & 63;
    const float* src = (g == 0) ? ghr : ((g == 1) ? ghz : ghh);
    odeP[idx] = packf16(src[i * 64 + 2 * p], src[i * 64 + 2 * p + 1]);
    bayP[idx] = packf16(gbWhh[r * 64 + 2 * p], gbWhh[r * 64 + 2 * p + 1]);
  }
  if (idx < 3 * 64 * 4) {
    int p = idx & 3, r = idx >> 2;
    float a = (2 * p < IN) ? gbWih[r * IN + 2 * p] : 0.0f;
    float b = (2 * p + 1 < IN) ? gbWih[r * IN + 2 * p + 1] : 0.0f;
    wihP[idx] = packf16(a, b);
  }
}

// One wave = TWO samples (interleaved chains hide LDS/trans latency).
// 512 blocks x 64 threads. ODE weights as f16-pairs ANCHORED in 96 VGPRs.
__global__ __launch_bounds__(64, 1) void evolve_kernel(
    const float* __restrict__ time_uniq,
    const float* __restrict__ X,
    const float* __restrict__ covs,
    const float* __restrict__ cov_W1, const float* __restrict__ cov_b1,
    const float* __restrict__ cov_W2, const float* __restrict__ cov_b2,
    const float* __restrict__ gb_bih, const float* __restrict__ gb_bhh,
    const float* __restrict__ gx_b,
    const unsigned* __restrict__ odeP, const unsigned* __restrict__ bayP,
    const unsigned* __restrict__ wihP,
    const int* __restrict__ evtab,
    float* __restrict__ hpath,
    int B, int NE, int n_steps, int IN, int COV)
{
  __shared__ unsigned sBW[3 * 64 * 32];          // Bayes pairs, slot-XOR swizzled (24KB)
  __shared__ int sStep[1024];
  __shared__ __align__(16) f16 sH16[2][64];
  __shared__ __align__(16) f16 sRH16[2][64];

  const int lane = threadIdx.x;
  const int b0 = blockIdx.x * 2, b1 = b0 + 1;
  const bool al0 = (b0 < B), al1 = (b1 < B);

  // stage Bayes pairs, slot swizzle slot' = slot ^ (row&7)
  for (int idx = lane; idx < 3 * 64 * 32; idx += 64) {
    int c = idx & 31, r = idx >> 5;
    int i = r & 63, s = c >> 2;
    sBW[r * 32 + (((s ^ (i & 7)) << 2) | (c & 3))] = bayP[idx];
  }
  // event schedule: wave-parallel prefix-max (verified R6/R7)
  {
    int pm = NEG_INF_I;
    int loc[16];
#pragma unroll
    for (int j = 0; j < 16; ++j) {
      int e = lane * 16 + j;
      int gv = NEG_INF_I;
      if (e < NE && e < 1024) {
        float tu = time_uniq[e];
        int k0 = (int)floorf((tu - EPS_F) * 100.0f) - 2;
        if (k0 < 0) k0 = 0;
        while ((float)k0 * DT_F + EPS_F < tu) ++k0;
        gv = k0 - e;
      }
      pm = max(pm, gv);
      loc[j] = pm;
    }
    int tot = pm;
#pragma unroll
    for (int off = 1; off < 64; off <<= 1) {
      int v = __shfl_up(tot, off);
      if (lane >= off) tot = max(tot, v);
    }
    int excl = __shfl_up(tot, 1);
    if (lane == 0) excl = NEG_INF_I;
#pragma unroll
    for (int j = 0; j < 16; ++j)
      sStep[lane * 16 + j] = lane * 16 + j + max(loc[j], excl);
  }
  __syncthreads();   // init only (single wave)

  // ---- ODE weights -> anchored VGPRs (96 regs) ----
  const uint4* odeQ = (const uint4*)odeP;
  uint4 WR[8], WZ[8], WU[8];
#pragma unroll
  for (int q = 0; q < 8; ++q) {
    WR[q] = odeQ[(0 * 64 + lane) * 8 + q];
    WZ[q] = odeQ[(1 * 64 + lane) * 8 + q];
    WU[q] = odeQ[(2 * 64 + lane) * 8 + q];
  }
#pragma unroll
  for (int q = 0; q < 8; ++q) { ANCH4(WR[q]); ANCH4(WZ[q]); ANCH4(WU[q]); }

  float xr = gx_b[lane], xz = gx_b[64 + lane], xh = gx_b[128 + lane];
  float crz_r = gb_bih[lane] + gb_bhh[lane];
  float crz_z = gb_bih[64 + lane] + gb_bhh[64 + lane];
  float bihn = gb_bih[128 + lane], bhhn = gb_bhh[128 + lane];
  ANCHF(xr); ANCHF(xz); ANCHF(xh); ANCHF(crz_r); ANCHF(crz_z);
  ANCHF(bihn); ANCHF(bhhn);

  // ---- h0 per sample ----
  float h0v = 0.0f, h1v = 0.0f;
#pragma unroll
  for (int s = 0; s < 2; ++s) {
    int b = b0 + s;
    if (b >= B) continue;
    float cacc = cov_b1[lane];
    for (int c = 0; c < COV; ++c)
      cacc = fmaf(covs[b * COV + c], cov_W1[lane * COV + c], cacc);
    float cl = fmaxf(cacc, 0.0f);
    float hacc = cov_b2[lane];
#pragma unroll
    for (int j = 0; j < 64; ++j)
      hacc = fmaf(rl(cl, j), cov_W2[lane * 64 + j], hacc);
    float hh = tanhf_fast(hacc);
    if (s == 0) h0v = hh; else h1v = hh;
  }
  sH16[0][lane] = (f16)h0v;
  sH16[1][lane] = (f16)h1v;

  // ---- event pipeline: per-sample v_cur/v_pipe, packed x ----
  int e_next = 0, s_next = 0x7fffffff;
  int vc0 = 0, vc1 = 0, vp0 = 0, vp1 = 0;
  unsigned xq0[4] = {0, 0, 0, 0}, xq1[4] = {0, 0, 0, 0};
  auto loadx = [&](int v, unsigned* xq) {
    const float* xp = X + (long)(v - 1) * IN;
    float xf[8];
#pragma unroll
    for (int kk = 0; kk < 8; ++kk) xf[kk] = (kk < IN) ? xp[kk] : 0.0f;
    xq[0] = packf16(xf[0], xf[1]); xq[1] = packf16(xf[2], xf[3]);
    xq[2] = packf16(xf[4], xf[5]); xq[3] = packf16(xf[6], xf[7]);
  };
  if (NE > 0) {
    s_next = sStep[0];
    if (al0) { vc0 = evtab[b0]; if (vc0 > 0) loadx(vc0, xq0); }
    if (al1) { vc1 = evtab[b1]; if (vc1 > 0) loadx(vc1, xq1); }
    if (NE > 1) {
      if (al0) vp0 = evtab[B + b0];
      if (al1) vp1 = evtab[B + b1];
    }
  }

  const uint4* hqA = (const uint4*)sH16[0];
  const uint4* hqB = (const uint4*)sH16[1];
  const uint4* rqA = (const uint4*)sRH16[0];
  const uint4* rqB = (const uint4*)sRH16[1];
  float* hp = hpath + (long)b0 * 64 + lane;    // s0 at hp[0], s1 at hp[64]
  const long rowstride = (long)B * 64;

#pragma unroll 1
  for (int k = 0; k < n_steps; ++k) {
    if (k == s_next) {                       // wave-uniform schedule
      // gru_bayes per firing sample (uses pre-event h image in LDS)
#pragma unroll
      for (int s = 0; s < 2; ++s) {
        int vc = (s == 0) ? vc0 : vc1;
        if (vc > 0) {
          const uint4* hq = (s == 0) ? hqA : hqB;
          const unsigned* xq = (s == 0) ? xq0 : xq1;
          const uint4* wihQ = (const uint4*)wihP;
          uint4 wxr = wihQ[lane], wxz = wihQ[64 + lane], wxn = wihQ[128 + lane];
          float ar = crz_r, az = crz_z, anh = bhhn, ani = bihn;
          ar = dot2(wxr.x, xq[0], ar); ar = dot2(wxr.y, xq[1], ar);
          ar = dot2(wxr.z, xq[2], ar); ar = dot2(wxr.w, xq[3], ar);
          az = dot2(wxz.x, xq[0], az); az = dot2(wxz.y, xq[1], az);
          az = dot2(wxz.z, xq[2], az); az = dot2(wxz.w, xq[3], az);
          ani = dot2(wxn.x, xq[0], ani); ani = dot2(wxn.y, xq[1], ani);
          ani = dot2(wxn.z, xq[2], ani); ani = dot2(wxn.w, xq[3], ani);
          float ar1 = 0.f, az1 = 0.f, an1 = 0.f;
#pragma unroll
          for (int q = 0; q < 8; ++q) {
            uint4 hh = hq[q];
            int sw = ((q ^ (lane & 7)) << 2);
            uint4 br = *(const uint4*)&sBW[(0 * 64 + lane) * 32 + sw];
            uint4 bz = *(const uint4*)&sBW[(1 * 64 + lane) * 32 + sw];
            uint4 bn = *(const uint4*)&sBW[(2 * 64 + lane) * 32 + sw];
            ar  = dot2(br.x, hh.x, ar);   ar1 = dot2(br.y, hh.y, ar1);
            ar  = dot2(br.z, hh.z, ar);   ar1 = dot2(br.w, hh.w, ar1);
            az  = dot2(bz.x, hh.x, az);   az1 = dot2(bz.y, hh.y, az1);
            az  = dot2(bz.z, hh.z, az);   az1 = dot2(bz.w, hh.w, az1);
            anh = dot2(bn.x, hh.x, anh);  an1 = dot2(bn.y, hh.y, an1);
            anh = dot2(bn.z, hh.z, anh);  an1 = dot2(bn.w, hh.w, an1);
          }
          float r = sigm(ar + ar1);
          float z = sigm(az + az1);
          float n = tanhf_fast(ani + r * (anh + an1));
          if (s == 0) { h0v = (1.0f - z) * n + z * h0v; sH16[0][lane] = (f16)h0v; }
          else        { h1v = (1.0f - z) * n + z * h1v; sH16[1][lane] = (f16)h1v; }
        }
      }
      ++e_next;
      if (e_next < NE && e_next < 1024) {
        s_next = sStep[e_next];
        vc0 = vp0; vc1 = vp1;
        if (vc0 > 0) loadx(vc0, xq0);
        if (vc1 > 0) loadx(vc1, xq1);
        if (e_next + 1 < NE) {
          if (al0) vp0 = evtab[(long)(e_next + 1) * B + b0];
          if (al1) vp1 = evtab[(long)(e_next + 1) * B + b1];
        } else { vp0 = 0; vp1 = 0; }
      } else {
        s_next = 0x7fffffff; vc0 = 0; vc1 = 0;
      }
    }

    // h_rec (post-event, pre-ODE)
    if (al0) hp[0] = h0v;
    if (al1) hp[64] = h1v;
    hp += rowstride;

    // ---- ODE: both samples interleaved ----
    uint4 hA[8], hB[8];
#pragma unroll
    for (int q = 0; q < 8; ++q) hA[q] = hqA[q];
#pragma unroll
    for (int q = 0; q < 8; ++q) hB[q] = hqB[q];

    float a0 = xr, a1 = 0.f, a2 = 0.f, a3 = 0.f;
    float c0 = xz, c1 = 0.f, c2 = 0.f, c3 = 0.f;
    float d0 = xr, d1 = 0.f, d2 = 0.f, d3 = 0.f;
    float e0 = xz, e1 = 0.f, e2 = 0.f, e3 = 0.f;
#pragma unroll
    for (int q = 0; q < 8; ++q) {
      uint4 ha = hA[q], hb = hB[q];
      a0 = dot2(WR[q].x, ha.x, a0); a1 = dot2(WR[q].y, ha.y, a1);
      a2 = dot2(WR[q].z, ha.z, a2); a3 = dot2(WR[q].w, ha.w, a3);
      c0 = dot2(WZ[q].x, ha.x, c0); c1 = dot2(WZ[q].y, ha.y, c1);
      c2 = dot2(WZ[q].z, ha.z, c2); c3 = dot2(WZ[q].w, ha.w, c3);
      d0 = dot2(WR[q].x, hb.x, d0); d1 = dot2(WR[q].y, hb.y, d1);
      d2 = dot2(WR[q].z, hb.z, d2); d3 = dot2(WR[q].w, hb.w, d3);
      e0 = dot2(WZ[q].x, hb.x, e0); e1 = dot2(WZ[q].y, hb.y, e1);
      e2 = dot2(WZ[q].z, hb.z, e2); e3 = dot2(WZ[q].w, hb.w, e3);
    }
    float r0 = sigm((a0 + a1) + (a2 + a3));
    float z0 = sigm((c0 + c1) + (c2 + c3));
    float r1 = sigm((d0 + d1) + (d2 + d3));
    float z1 = sigm((e0 + e1) + (e2 + e3));
    sRH16[0][lane] = (f16)(r0 * h0v);
    sRH16[1][lane] = (f16)(r1 * h1v);

    float u0a = xh, u0b = 0.f, u0c = 0.f, u0d = 0.f;
    float u1a = xh, u1b = 0.f, u1c = 0.f, u1d = 0.f;
#pragma unroll
    for (int q = 0; q < 8; ++q) {
      uint4 ra = rqA[q], rb = rqB[q];
      u0a = dot2(WU[q].x, ra.x, u0a); u0b = dot2(WU[q].y, ra.y, u0b);
      u0c = dot2(WU[q].z, ra.z, u0c); u0d = dot2(WU[q].w, ra.w, u0d);
      u1a = dot2(WU[q].x, rb.x, u1a); u1b = dot2(WU[q].y, rb.y, u1b);
      u1c = dot2(WU[q].z, rb.z, u1c); u1d = dot2(WU[q].w, rb.w, u1d);
    }
    float u0 = tanhf_fast((u0a + u0b) + (u0c + u0d));
    float u1 = tanhf_fast((u1a + u1b) + (u1c + u1d));
    h0v = fmaf(DT_F * (1.0f - z0), u0 - h0v, h0v);
    h1v = fmaf(DT_F * (1.0f - z1), u1 - h1v, h1v);
    sH16[0][lane] = (f16)h0v;
    sH16[1][lane] = (f16)h1v;
  }

  if (al0) hp[0] = h0v;    // h_last
  if (al1) hp[64] = h1v;
}

// out[row] = relu(h[row] @ W1^T + b1) @ W2^T + b2, rows = (n_steps+1)*B
__global__ __launch_bounds__(256, 2) void head_kernel(
    const float* __restrict__ hpath, const float* __restrict__ W1,
    const float* __restrict__ b1, const float* __restrict__ W2,
    const float* __restrict__ b2, float* __restrict__ out, long nrows)
{
  __shared__ __align__(16) float sW1[64 * 128];
  __shared__ __align__(16) float sH[64 * 128];
  int tid = threadIdx.x;
  for (int idx = tid; idx < 128 * 64; idx += 256) {
    int oc = idx >> 6, j = idx & 63;
    sW1[j * 128 + oc] = W1[idx];
  }
  long row0 = (long)blockIdx.x * 128;
  for (int idx = tid; idx < 128 * 64; idx += 256) {
    int r = idx >> 6, j = idx & 63;
    long row = row0 + r;
    sH[j * 128 + r] = (row < nrows) ? hpath[row * 64 + j] : 0.0f;
  }
  __syncthreads();

  int tr = tid >> 4, tc = tid & 15;
  int r0 = tr * 8, oc0 = tc * 8;
  float acc[8][8];
#pragma unroll
  for (int s = 0; s < 8; ++s)
#pragma unroll
    for (int u = 0; u < 8; ++u) acc[s][u] = 0.0f;

#pragma unroll 4
  for (int j = 0; j < 64; ++j) {
    float4 ha = *(const float4*)&sH[j * 128 + r0];
    float4 hb = *(const float4*)&sH[j * 128 + r0 + 4];
    float4 wa = *(const float4*)&sW1[j * 128 + oc0];
    float4 wb = *(const float4*)&sW1[j * 128 + oc0 + 4];
    float hv[8] = {ha.x, ha.y, ha.z, ha.w, hb.x, hb.y, hb.z, hb.w};
    float wv[8] = {wa.x, wa.y, wa.z, wa.w, wb.x, wb.y, wb.z, wb.w};
#pragma unroll
    for (int s = 0; s < 8; ++s)
#pragma unroll
      for (int u = 0; u < 8; ++u)
        acc[s][u] = fmaf(hv[s], wv[u], acc[s][u]);
  }

  float p[8][2];
#pragma unroll
  for (int s = 0; s < 8; ++s) { p[s][0] = 0.0f; p[s][1] = 0.0f; }
#pragma unroll
  for (int u = 0; u < 8; ++u) {
    float b1v = b1[oc0 + u];
    float w2a = W2[oc0 + u];
    float w2b = W2[128 + oc0 + u];
#pragma unroll
    for (int s = 0; s < 8; ++s) {
      float o = fmaxf(acc[s][u] + b1v, 0.0f);
      p[s][0] = fmaf(o, w2a, p[s][0]);
      p[s][1] = fmaf(o, w2b, p[s][1]);
    }
  }
#pragma unroll
  for (int off = 1; off < 16; off <<= 1) {
#pragma unroll
    for (int s = 0; s < 8; ++s) {
      p[s][0] += __shfl_xor(p[s][0], off);
      p[s][1] += __shfl_xor(p[s][1], off);
    }
  }
  if (tc == 0) {
    float b20 = b2[0], b21 = b2[1];
#pragma unroll
    for (int s = 0; s < 8; ++s) {
      long row = row0 + r0 + s;
      if (row < nrows) {
        out[row * 2 + 0] = p[s][0] + b20;
        out[row * 2 + 1] = p[s][1] + b21;
      }
    }
  }
}

extern "C" void kernel_launch(void* const* d_in, const int* in_sizes, int n_in,
                              void* d_out, int out_size, void* d_ws, size_t ws_size,
                              hipStream_t stream) {
  const float* time_uniq  = (const float*)d_in[0];
  const int*   time_ptr   = (const int*)d_in[1];
  const float* X          = (const float*)d_in[2];
  const int*   sample_ids = (const int*)d_in[3];
  const float* covs       = (const float*)d_in[4];
  const float* cov_W1     = (const float*)d_in[6];
  const float* cov_b1     = (const float*)d_in[7];
  const float* cov_W2     = (const float*)d_in[8];
  const float* cov_b2     = (const float*)d_in[9];
  const float* gb_Wih     = (const float*)d_in[10];
  const float* gb_Whh     = (const float*)d_in[11];
  const float* gb_bih     = (const float*)d_in[12];
  const float* gb_bhh     = (const float*)d_in[13];
  const float* gx_b       = (const float*)d_in[15];
  const float* ghr_W      = (const float*)d_in[16];
  const float* ghz_W      = (const float*)d_in[17];
  const float* ghh_W      = (const float*)d_in[18];
  const float* out_W1     = (const float*)d_in[19];
  const float* out_b1     = (const float*)d_in[20];
  const float* out_W2     = (const float*)d_in[21];
  const float* out_b2     = (const float*)d_in[22];

  int NE   = in_sizes[0];
  int TOT  = in_sizes[3];
  int IN   = in_sizes[2] / TOT;
  int CH   = in_sizes[7];
  int COV  = in_sizes[6] / CH;
  int B    = in_sizes[4] / COV;
  int OUTD = in_sizes[22];
  int n_steps = out_size / (B * OUTD) - 1;
  int OPE  = TOT / NE;

  char* ws = (char*)d_ws;
  int* evtab = (int*)ws;
  size_t evbytes = (size_t)NE * (size_t)B * sizeof(int);
  size_t off1 = (evbytes + 255) & ~(size_t)255;
  unsigned* odeP = (unsigned*)(ws + off1);
  unsigned* bayP = odeP + 3 * 64 * 32;
  unsigned* wihP = bayP + 3 * 64 * 32;
  size_t off2 = off1 + (((3 * 64 * 32 * 2 + 3 * 64 * 4) * sizeof(unsigned) + 255) & ~(size_t)255);
  float* hpath = (float*)(ws + off2);

  hipMemsetAsync(evtab, 0, evbytes, stream);
  build_evtab_kernel<<<NE, 256, 0, stream>>>(sample_ids, time_ptr, evtab, B, OPE);
  pack_pairs_kernel<<<24, 256, 0, stream>>>(ghr_W, ghz_W, ghh_W, gb_Whh, gb_Wih,
                                            odeP, bayP, wihP, IN);
  evolve_kernel<<<(B + 1) / 2, 64, 0, stream>>>(
      time_uniq, X, covs, cov_W1, cov_b1, cov_W2, cov_b2,
      gb_bih, gb_bhh, gx_b, odeP, bayP, wihP,
      evtab, hpath, B, NE, n_steps, IN, COV);
  long nrows = (long)(n_steps + 1) * B;
  int hb = (int)((nrows + 127) / 128);
  head_kernel<<<hb, 256, 0, stream>>>(hpath, out_W1, out_b1, out_W2, out_b2,
                                      (float*)d_out, nrows);
}

// Round 9
// 453.849 us; speedup vs baseline: 2.1030x; 2.1030x over previous
//
#include <hip/hip_runtime.h>

#define DT_F 0.01f
#define EPS_F 1e-5f
#define NEG_INF_I (-1073741824)

typedef _Float16 f16;
typedef _Float16 f16x2 __attribute__((ext_vector_type(2)));
typedef _Float16 f16x8 __attribute__((ext_vector_type(8)));
typedef float f32x4 __attribute__((ext_vector_type(4)));

#define MFMA16(a, b, c) __builtin_amdgcn_mfma_f32_16x16x32_f16((a), (b), (c), 0, 0, 0)

__device__ __forceinline__ float rl(float v, int l) {
  return __int_as_float(__builtin_amdgcn_readlane(__float_as_int(v), l));
}
__device__ __forceinline__ float sigm(float x) {
  float e = __builtin_amdgcn_exp2f(-1.442695041f * x);
  return __builtin_amdgcn_rcpf(1.0f + e);
}
__device__ __forceinline__ float tanhf_fast(float x) {
  float e = __builtin_amdgcn_exp2f(2.885390082f * x);
  return fmaf(-2.0f, __builtin_amdgcn_rcpf(e + 1.0f), 1.0f);
}
__device__ __forceinline__ float dot2(unsigned w, unsigned h, float acc) {
  return __builtin_amdgcn_fdot2(__builtin_bit_cast(f16x2, w),
                                __builtin_bit_cast(f16x2, h), acc, false);
}
__device__ __forceinline__ unsigned packf16(float a, float b) {
  return __builtin_bit_cast(unsigned, __builtin_amdgcn_cvt_pkrtz(a, b));
}
// per-iteration VGPR pin: forces the value into a VGPR-class register here
#define PINQ(v) asm volatile("" : "+v"((v).x), "+v"((v).y), "+v"((v).z), "+v"((v).w))

// evtab[k*B + sid] = (last obs index in event k's window with sample_ids==sid) + 1, or 0.
__global__ void build_evtab_kernel(const int* __restrict__ sample_ids,
                                   const int* __restrict__ time_ptr,
                                   int* __restrict__ evtab, int B, int ope) {
  int k = blockIdx.x;
  int base = time_ptr[k];
  for (int t = threadIdx.x; t < ope; t += blockDim.x) {
    int obs = base + t;
    int sid = sample_ids[obs];
    atomicMax(&evtab[k * B + sid], obs + 1);   // last occurrence wins
  }
}

// f16-pair packing (verified R7)
__global__ void pack_pairs_kernel(const float* __restrict__ ghr,
                                  const float* __restrict__ ghz,
                                  const float* __restrict__ ghh,
                                  const float* __restrict__ gbWhh,
                                  const float* __restrict__ gbWih,
                                  unsigned* __restrict__ odeP,
                                  unsigned* __restrict__ bayP,
                                  unsigned* __restrict__ wihP, int IN) {
  int idx = blockIdx.x * 256 + threadIdx.x;
  if (idx < 3 * 64 * 32) {
    int p = idx & 31, r = idx >> 5;
    int g = r >> 6, i = r & 63;
    const float* src = (g == 0) ? ghr : ((g == 1) ? ghz : ghh);
    odeP[idx] = packf16(src[i * 64 + 2 * p], src[i * 64 + 2 * p + 1]);
    bayP[idx] = packf16(gbWhh[r * 64 + 2 * p], gbWhh[r * 64 + 2 * p + 1]);
  }
  if (idx < 3 * 64 * 4) {
    int p = idx & 3, r = idx >> 2;
    float a = (2 * p < IN) ? gbWih[r * IN + 2 * p] : 0.0f;
    float b = (2 * p + 1 < IN) ? gbWih[r * IN + 2 * p + 1] : 0.0f;
    wihP[idx] = packf16(a, b);
  }
}

// W1 -> MFMA B-fragments (layout HW-verified in R5): f = 2t+kf;
// lane l holds W1[n][k], n = 16t+(l&15), k = 8*(l>>4)+j+32*kf.
__global__ void pack_head_kernel(const float* __restrict__ W1, f16* __restrict__ w1P) {
  int f = blockIdx.x;       // 0..15
  int l = threadIdx.x;      // 0..63
  int t = f >> 1, kf = f & 1;
  int n = 16 * t + (l & 15);
  for (int j = 0; j < 8; ++j) {
    int k = 8 * (l >> 4) + j + 32 * kf;
    w1P[f * 512 + l * 8 + j] = (f16)W1[n * 64 + k];
  }
}

// One wave per sample, 4 waves/block, 256 blocks, zero in-loop barriers (R7 base).
// + per-iteration weight pins, next-h LDS prefetch, f16 hpath stores.
__global__ __launch_bounds__(256, 1) void evolve_kernel(
    const float* __restrict__ time_uniq,
    const float* __restrict__ X,
    const float* __restrict__ covs,
    const float* __restrict__ cov_W1, const float* __restrict__ cov_b1,
    const float* __restrict__ cov_W2, const float* __restrict__ cov_b2,
    const float* __restrict__ gb_bih, const float* __restrict__ gb_bhh,
    const float* __restrict__ gx_b,
    const unsigned* __restrict__ odeP, const unsigned* __restrict__ bayP,
    const unsigned* __restrict__ wihP,
    const int* __restrict__ evtab,
    f16* __restrict__ hp16,
    int B, int NE, int n_steps, int IN, int COV)
{
  __shared__ unsigned sBW[3 * 64 * 32];          // Bayes pairs, slot-XOR swizzled (24KB)
  __shared__ int sStep[1024];
  __shared__ __align__(16) f16 sH16[4][64];
  __shared__ __align__(16) f16 sRH16[4][64];

  const int tid = threadIdx.x;
  const int wid = tid >> 6, lane = tid & 63;
  const int b = blockIdx.x * 4 + wid;
  const bool alive = (b < B);

  for (int idx = tid; idx < 3 * 64 * 32; idx += 256) {
    int c = idx & 31, r = idx >> 5;
    int i = r & 63, s = c >> 2;
    sBW[r * 32 + (((s ^ (i & 7)) << 2) | (c & 3))] = bayP[idx];
  }
  if (wid == 0) {     // wave-parallel prefix-max event schedule (verified R6/R7)
    int pm = NEG_INF_I;
    int loc[16];
#pragma unroll
    for (int j = 0; j < 16; ++j) {
      int e = lane * 16 + j;
      int gv = NEG_INF_I;
      if (e < NE && e < 1024) {
        float tu = time_uniq[e];
        int k0 = (int)floorf((tu - EPS_F) * 100.0f) - 2;
        if (k0 < 0) k0 = 0;
        while ((float)k0 * DT_F + EPS_F < tu) ++k0;
        gv = k0 - e;
      }
      pm = max(pm, gv);
      loc[j] = pm;
    }
    int tot = pm;
#pragma unroll
    for (int off = 1; off < 64; off <<= 1) {
      int v = __shfl_up(tot, off);
      if (lane >= off) tot = max(tot, v);
    }
    int excl = __shfl_up(tot, 1);
    if (lane == 0) excl = NEG_INF_I;
#pragma unroll
    for (int j = 0; j < 16; ++j)
      sStep[lane * 16 + j] = lane * 16 + j + max(loc[j], excl);
  }
  __syncthreads();   // init only

  const uint4* odeQ = (const uint4*)odeP;
  uint4 WR[8], WZ[8], WU[8];
#pragma unroll
  for (int q = 0; q < 8; ++q) {
    WR[q] = odeQ[(0 * 64 + lane) * 8 + q];
    WZ[q] = odeQ[(1 * 64 + lane) * 8 + q];
    WU[q] = odeQ[(2 * 64 + lane) * 8 + q];
  }
  const uint4* wihQ = (const uint4*)wihP;

  const float xr = gx_b[lane], xz = gx_b[64 + lane], xh = gx_b[128 + lane];
  const float crz_r = gb_bih[lane] + gb_bhh[lane];
  const float crz_z = gb_bih[64 + lane] + gb_bhh[64 + lane];
  const float bihn = gb_bih[128 + lane], bhhn = gb_bhh[128 + lane];

  // ---- h0 ----
  float h = 0.0f;
  if (alive) {
    float cacc = cov_b1[lane];
    for (int c = 0; c < COV; ++c)
      cacc = fmaf(covs[b * COV + c], cov_W1[lane * COV + c], cacc);
    float cl = fmaxf(cacc, 0.0f);
    float hacc = cov_b2[lane];
#pragma unroll
    for (int j = 0; j < 64; ++j)
      hacc = fmaf(rl(cl, j), cov_W2[lane * 64 + j], hacc);
    h = tanhf_fast(hacc);
  }
  sH16[wid][lane] = (f16)h;

  // ---- event pipeline (2-deep) ----
  int e_next = 0, s_next = 0x7fffffff, v_cur = 0, v_pipe = 0;
  float xf[8];
#pragma unroll
  for (int kk = 0; kk < 8; ++kk) xf[kk] = 0.0f;
  if (alive && NE > 0) {
    s_next = sStep[0];
    v_cur = evtab[b];
    if (v_cur > 0) {
      const float* xp = X + (long)(v_cur - 1) * IN;
#pragma unroll
      for (int kk = 0; kk < 8; ++kk) xf[kk] = (kk < IN) ? xp[kk] : 0.0f;
    }
    v_pipe = (NE > 1) ? evtab[B + b] : 0;
  } else if (NE > 0) {
    s_next = sStep[0];
  }

  const uint4* hq4 = (const uint4*)sH16[wid];
  const uint4* rq4 = (const uint4*)sRH16[wid];
  f16* hps = hp16 + (long)b * 64 + lane;
  const long rowstride = (long)B * 64;

  uint4 hpre[8];
#pragma unroll
  for (int q = 0; q < 8; ++q) hpre[q] = hq4[q];

#pragma unroll 1
  for (int k = 0; k < n_steps; ++k) {
    // pin ODE weights into VGPRs every iteration
#pragma unroll
    for (int q = 0; q < 8; ++q) { PINQ(WR[q]); PINQ(WZ[q]); PINQ(WU[q]); }

    if (k == s_next) {                       // wave-uniform schedule
      if (v_cur > 0) {                       // this sample fires (wave-uniform)
        unsigned xp0 = packf16(xf[0], xf[1]), xp1 = packf16(xf[2], xf[3]);
        unsigned xp2 = packf16(xf[4], xf[5]), xp3 = packf16(xf[6], xf[7]);
        uint4 wxr = wihQ[lane], wxz = wihQ[64 + lane], wxn = wihQ[128 + lane];
        float ar = crz_r, az = crz_z, anh = bhhn, ani = bihn;
        ar = dot2(wxr.x, xp0, ar); ar = dot2(wxr.y, xp1, ar);
        ar = dot2(wxr.z, xp2, ar); ar = dot2(wxr.w, xp3, ar);
        az = dot2(wxz.x, xp0, az); az = dot2(wxz.y, xp1, az);
        az = dot2(wxz.z, xp2, az); az = dot2(wxz.w, xp3, az);
        ani = dot2(wxn.x, xp0, ani); ani = dot2(wxn.y, xp1, ani);
        ani = dot2(wxn.z, xp2, ani); ani = dot2(wxn.w, xp3, ani);
        float ar1 = 0.f, az1 = 0.f, an1 = 0.f;
#pragma unroll
        for (int q = 0; q < 8; ++q) {
          uint4 hh = hpre[q];                 // h pairs already in registers
          int sw = ((q ^ (lane & 7)) << 2);
          uint4 br = *(const uint4*)&sBW[(0 * 64 + lane) * 32 + sw];
          uint4 bz = *(const uint4*)&sBW[(1 * 64 + lane) * 32 + sw];
          uint4 bn = *(const uint4*)&sBW[(2 * 64 + lane) * 32 + sw];
          ar  = dot2(br.x, hh.x, ar);   ar1 = dot2(br.y, hh.y, ar1);
          ar  = dot2(br.z, hh.z, ar);   ar1 = dot2(br.w, hh.w, ar1);
          az  = dot2(bz.x, hh.x, az);   az1 = dot2(bz.y, hh.y, az1);
          az  = dot2(bz.z, hh.z, az);   az1 = dot2(bz.w, hh.w, az1);
          anh = dot2(bn.x, hh.x, anh);  an1 = dot2(bn.y, hh.y, an1);
          anh = dot2(bn.z, hh.z, anh);  an1 = dot2(bn.w, hh.w, an1);
        }
        float r = sigm(ar + ar1);
        float z = sigm(az + az1);
        float n = tanhf_fast(ani + r * (anh + an1));
        h = (1.0f - z) * n + z * h;
        sH16[wid][lane] = (f16)h;
#pragma unroll
        for (int q = 0; q < 8; ++q) hpre[q] = hq4[q];   // refresh broadcast
      }
      ++e_next;
      if (e_next < NE && e_next < 1024) {
        s_next = sStep[e_next];
        v_cur = v_pipe;
        if (v_cur > 0) {
          const float* xp = X + (long)(v_cur - 1) * IN;
#pragma unroll
          for (int kk = 0; kk < 8; ++kk) xf[kk] = (kk < IN) ? xp[kk] : 0.0f;
        }
        v_pipe = (e_next + 1 < NE) ? evtab[(long)(e_next + 1) * B + b] : 0;
      } else {
        s_next = 0x7fffffff;
        v_cur = 0;
      }
    }

    if (alive)
      hps[(long)k * rowstride] = (f16)h;     // h_rec (post-event, pre-ODE), f16

    // ---- phase A: r,z (weights in pinned VGPRs, h pairs prefetched) ----
    float ar0 = xr, ar1 = 0.f, ar2 = 0.f, ar3 = 0.f;
    float az0 = xz, az1 = 0.f, az2 = 0.f, az3 = 0.f;
#pragma unroll
    for (int q = 0; q < 8; ++q) {
      uint4 hp = hpre[q];
      ar0 = dot2(WR[q].x, hp.x, ar0); ar1 = dot2(WR[q].y, hp.y, ar1);
      ar2 = dot2(WR[q].z, hp.z, ar2); ar3 = dot2(WR[q].w, hp.w, ar3);
      az0 = dot2(WZ[q].x, hp.x, az0); az1 = dot2(WZ[q].y, hp.y, az1);
      az2 = dot2(WZ[q].z, hp.z, az2); az3 = dot2(WZ[q].w, hp.w, az3);
    }
    float r = sigm((ar0 + ar1) + (ar2 + ar3));
    float z = sigm((az0 + az1) + (az2 + az3));
    sRH16[wid][lane] = (f16)(r * h);

    // ---- phase B: u matvec (r*h broadcast; one exposed LDS round-trip) ----
    float au0 = xh, au1 = 0.f, au2 = 0.f, au3 = 0.f;
#pragma unroll
    for (int q = 0; q < 8; ++q) {
      uint4 rp = rq4[q];
      au0 = dot2(WU[q].x, rp.x, au0); au1 = dot2(WU[q].y, rp.y, au1);
      au2 = dot2(WU[q].z, rp.z, au2); au3 = dot2(WU[q].w, rp.w, au3);
    }
    float u = tanhf_fast((au0 + au1) + (au2 + au3));
    h = fmaf(DT_F * (1.0f - z), u - h, h);
    sH16[wid][lane] = (f16)h;
#pragma unroll
    for (int q = 0; q < 8; ++q) hpre[q] = hq4[q];   // prefetch next step's h
  }

  if (alive)
    hps[(long)n_steps * rowstride] = (f16)h;   // h_last
}

// MFMA head: out[row] = relu(h[row] @ W1^T + b1) @ W2^T + b2.
// A = hpath f16 rows (M=16/group), B = prepacked W1 frags, C layout per R5.
__global__ __launch_bounds__(256, 4) void head_mfma_kernel(
    const f16* __restrict__ hp16, const f16* __restrict__ w1P,
    const float* __restrict__ b1, const float* __restrict__ W2,
    const float* __restrict__ b2, float* __restrict__ out, long nrows)
{
  const int wq = threadIdx.x >> 6, lane = threadIdx.x & 63;
  const int col = lane & 15;
  const long rowbase = ((long)blockIdx.x * 4 + wq) * 64;   // 64 rows per wave

  f16x8 Wf[8][2];
#pragma unroll
  for (int t = 0; t < 8; ++t)
#pragma unroll
    for (int kf = 0; kf < 2; ++kf)
      Wf[t][kf] = ((const f16x8*)w1P)[(2 * t + kf) * 64 + lane];

  float b1v[8], w2a[8], w2b[8];
#pragma unroll
  for (int t = 0; t < 8; ++t) {
    b1v[t] = b1[16 * t + col];
    w2a[t] = W2[16 * t + col];
    w2b[t] = W2[128 + 16 * t + col];
  }
  const float b20 = b2[0], b21 = b2[1];

#pragma unroll 1
  for (int g = 0; g < 4; ++g) {
    long row0 = rowbase + g * 16;
    long arow = row0 + col;
    f16x8 aH0 = {0, 0, 0, 0, 0, 0, 0, 0}, aH1 = aH0;
    if (arow < nrows) {
      const f16x8* ap = (const f16x8*)(hp16 + arow * 64);
      aH0 = ap[lane >> 4];
      aH1 = ap[(lane >> 4) + 4];
    }
    float p0[4] = {0.f, 0.f, 0.f, 0.f}, p1[4] = {0.f, 0.f, 0.f, 0.f};
#pragma unroll
    for (int t = 0; t < 8; ++t) {
      f32x4 c = {0.f, 0.f, 0.f, 0.f};
      c = MFMA16(aH0, Wf[t][0], c);
      c = MFMA16(aH1, Wf[t][1], c);
#pragma unroll
      for (int i = 0; i < 4; ++i) {
        float o = fmaxf(c[i] + b1v[t], 0.0f);
        p0[i] = fmaf(o, w2a[t], p0[i]);
        p1[i] = fmaf(o, w2b[t], p1[i]);
      }
    }
#pragma unroll
    for (int off = 1; off < 16; off <<= 1) {
#pragma unroll
      for (int i = 0; i < 4; ++i) {
        p0[i] += __shfl_xor(p0[i], off);
        p1[i] += __shfl_xor(p1[i], off);
      }
    }
    if (col == 0) {
#pragma unroll
      for (int i = 0; i < 4; ++i) {
        long row = row0 + (lane >> 4) * 4 + i;
        if (row < nrows) {
          out[row * 2 + 0] = p0[i] + b20;
          out[row * 2 + 1] = p1[i] + b21;
        }
      }
    }
  }
}

extern "C" void kernel_launch(void* const* d_in, const int* in_sizes, int n_in,
                              void* d_out, int out_size, void* d_ws, size_t ws_size,
                              hipStream_t stream) {
  const float* time_uniq  = (const float*)d_in[0];
  const int*   time_ptr   = (const int*)d_in[1];
  const float* X          = (const float*)d_in[2];
  const int*   sample_ids = (const int*)d_in[3];
  const float* covs       = (const float*)d_in[4];
  const float* cov_W1     = (const float*)d_in[6];
  const float* cov_b1     = (const float*)d_in[7];
  const float* cov_W2     = (const float*)d_in[8];
  const float* cov_b2     = (const float*)d_in[9];
  const float* gb_Wih     = (const float*)d_in[10];
  const float* gb_Whh     = (const float*)d_in[11];
  const float* gb_bih     = (const float*)d_in[12];
  const float* gb_bhh     = (const float*)d_in[13];
  const float* gx_b       = (const float*)d_in[15];
  const float* ghr_W      = (const float*)d_in[16];
  const float* ghz_W      = (const float*)d_in[17];
  const float* ghh_W      = (const float*)d_in[18];
  const float* out_W1     = (const float*)d_in[19];
  const float* out_b1     = (const float*)d_in[20];
  const float* out_W2     = (const float*)d_in[21];
  const float* out_b2     = (const float*)d_in[22];

  int NE   = in_sizes[0];
  int TOT  = in_sizes[3];
  int IN   = in_sizes[2] / TOT;
  int CH   = in_sizes[7];
  int COV  = in_sizes[6] / CH;
  int B    = in_sizes[4] / COV;
  int OUTD = in_sizes[22];
  int n_steps = out_size / (B * OUTD) - 1;
  int OPE  = TOT / NE;

  char* ws = (char*)d_ws;
  int* evtab = (int*)ws;
  size_t evbytes = (size_t)NE * (size_t)B * sizeof(int);
  size_t off1 = (evbytes + 255) & ~(size_t)255;
  unsigned* odeP = (unsigned*)(ws + off1);
  unsigned* bayP = odeP + 3 * 64 * 32;
  unsigned* wihP = bayP + 3 * 64 * 32;
  size_t off2 = off1 + (((3 * 64 * 32 * 2 + 3 * 64 * 4) * sizeof(unsigned) + 255) & ~(size_t)255);
  f16* w1P = (f16*)(ws + off2);
  size_t off3 = off2 + ((16 * 512 * sizeof(f16) + 255) & ~(size_t)255);
  f16* hp16 = (f16*)(ws + off3);

  hipMemsetAsync(evtab, 0, evbytes, stream);
  build_evtab_kernel<<<NE, 256, 0, stream>>>(sample_ids, time_ptr, evtab, B, OPE);
  pack_pairs_kernel<<<24, 256, 0, stream>>>(ghr_W, ghz_W, ghh_W, gb_Whh, gb_Wih,
                                            odeP, bayP, wihP, IN);
  pack_head_kernel<<<16, 64, 0, stream>>>(out_W1, w1P);
  evolve_kernel<<<(B + 3) / 4, 256, 0, stream>>>(
      time_uniq, X, covs, cov_W1, cov_b1, cov_W2, cov_b2,
      gb_bih, gb_bhh, gx_b, odeP, bayP, wihP,
      evtab, hp16, B, NE, n_steps, IN, COV);
  long nrows = (long)(n_steps + 1) * B;
  int hb = (int)((nrows + 255) / 256);
  head_mfma_kernel<<<hb, 256, 0, stream>>>(hp16, w1P, out_b1, out_W2, out_b2,
                                           (float*)d_out, nrows);
}

// Round 10
// 447.304 us; speedup vs baseline: 2.1338x; 1.0146x over previous
//
#include <hip/hip_runtime.h>

#define DT_F 0.01f
#define EPS_F 1e-5f
#define NEG_INF_I (-1073741824)

typedef _Float16 f16;
typedef _Float16 f16x2 __attribute__((ext_vector_type(2)));
typedef _Float16 f16x8 __attribute__((ext_vector_type(8)));
typedef float f32x4 __attribute__((ext_vector_type(4)));

#define MFMA16(a, b, c) __builtin_amdgcn_mfma_f32_16x16x32_f16((a), (b), (c), 0, 0, 0)

__device__ __forceinline__ float rl(float v, int l) {
  return __int_as_float(__builtin_amdgcn_readlane(__float_as_int(v), l));
}
__device__ __forceinline__ float sigm(float x) {
  float e = __builtin_amdgcn_exp2f(-1.442695041f * x);
  return __builtin_amdgcn_rcpf(1.0f + e);
}
__device__ __forceinline__ float tanhf_fast(float x) {
  float e = __builtin_amdgcn_exp2f(2.885390082f * x);
  return fmaf(-2.0f, __builtin_amdgcn_rcpf(e + 1.0f), 1.0f);
}
__device__ __forceinline__ float dot2(unsigned w, unsigned h, float acc) {
  return __builtin_amdgcn_fdot2(__builtin_bit_cast(f16x2, w),
                                __builtin_bit_cast(f16x2, h), acc, false);
}
__device__ __forceinline__ unsigned packf16(float a, float b) {
  return __builtin_bit_cast(unsigned, __builtin_amdgcn_cvt_pkrtz(a, b));
}
// ONCE-anchor: re-defines the value via opaque asm so the original global
// load cannot be rematerialized/sunk into the loop.
#define ANCH4(v) asm volatile("" : "+v"((v).x), "+v"((v).y), "+v"((v).z), "+v"((v).w))
#define ANCHF(v) asm volatile("" : "+v"(v))

// evtab[k*B + sid] = (last obs index in event k's window with sample_ids==sid) + 1, or 0.
__global__ void build_evtab_kernel(const int* __restrict__ sample_ids,
                                   const int* __restrict__ time_ptr,
                                   int* __restrict__ evtab, int B, int ope) {
  int k = blockIdx.x;
  int base = time_ptr[k];
  for (int t = threadIdx.x; t < ope; t += blockDim.x) {
    int obs = base + t;
    int sid = sample_ids[obs];
    atomicMax(&evtab[k * B + sid], obs + 1);   // last occurrence wins
  }
}

// f16-pair packing (verified R7)
__global__ void pack_pairs_kernel(const float* __restrict__ ghr,
                                  const float* __restrict__ ghz,
                                  const float* __restrict__ ghh,
                                  const float* __restrict__ gbWhh,
                                  const float* __restrict__ gbWih,
                                  unsigned* __restrict__ odeP,
                                  unsigned* __restrict__ bayP,
                                  unsigned* __restrict__ wihP, int IN) {
  int idx = blockIdx.x * 256 + threadIdx.x;
  if (idx < 3 * 64 * 32) {
    int p = idx & 31, r = idx >> 5;
    int g = r >> 6, i = r & 63;
    const float* src = (g == 0) ? ghr : ((g == 1) ? ghz : ghh);
    odeP[idx] = packf16(src[i * 64 + 2 * p], src[i * 64 + 2 * p + 1]);
    bayP[idx] = packf16(gbWhh[r * 64 + 2 * p], gbWhh[r * 64 + 2 * p + 1]);
  }
  if (idx < 3 * 64 * 4) {
    int p = idx & 3, r = idx >> 2;
    float a = (2 * p < IN) ? gbWih[r * IN + 2 * p] : 0.0f;
    float b = (2 * p + 1 < IN) ? gbWih[r * IN + 2 * p + 1] : 0.0f;
    wihP[idx] = packf16(a, b);
  }
}

// W1 -> MFMA B-fragments (layout HW-verified in R5)
__global__ void pack_head_kernel(const float* __restrict__ W1, f16* __restrict__ w1P) {
  int f = blockIdx.x;       // 0..15
  int l = threadIdx.x;      // 0..63
  int t = f >> 1, kf = f & 1;
  int n = 16 * t + (l & 15);
  for (int j = 0; j < 8; ++j) {
    int k = 8 * (l >> 4) + j + 32 * kf;
    w1P[f * 512 + l * 8 + j] = (f16)W1[n * 64 + k];
  }
}

// One wave per sample, 4 waves/block, 256 blocks, zero in-loop barriers.
// ODE weights anchored ONCE before the loop (kills L2 re-fetch); h broadcast
// read directly from LDS each phase.
__global__ __launch_bounds__(256, 1) void evolve_kernel(
    const float* __restrict__ time_uniq,
    const float* __restrict__ X,
    const float* __restrict__ covs,
    const float* __restrict__ cov_W1, const float* __restrict__ cov_b1,
    const float* __restrict__ cov_W2, const float* __restrict__ cov_b2,
    const float* __restrict__ gb_bih, const float* __restrict__ gb_bhh,
    const float* __restrict__ gx_b,
    const unsigned* __restrict__ odeP, const unsigned* __restrict__ bayP,
    const unsigned* __restrict__ wihP,
    const int* __restrict__ evtab,
    f16* __restrict__ hp16,
    int B, int NE, int n_steps, int IN, int COV)
{
  __shared__ unsigned sBW[3 * 64 * 32];          // Bayes pairs, slot-XOR swizzled (24KB)
  __shared__ int sStep[1024];
  __shared__ __align__(16) f16 sH16[4][64];
  __shared__ __align__(16) f16 sRH16[4][64];

  const int tid = threadIdx.x;
  const int wid = tid >> 6, lane = tid & 63;
  const int b = blockIdx.x * 4 + wid;
  const bool alive = (b < B);

  for (int idx = tid; idx < 3 * 64 * 32; idx += 256) {
    int c = idx & 31, r = idx >> 5;
    int i = r & 63, s = c >> 2;
    sBW[r * 32 + (((s ^ (i & 7)) << 2) | (c & 3))] = bayP[idx];
  }
  if (wid == 0) {     // wave-parallel prefix-max event schedule (verified R6/R7)
    int pm = NEG_INF_I;
    int loc[16];
#pragma unroll
    for (int j = 0; j < 16; ++j) {
      int e = lane * 16 + j;
      int gv = NEG_INF_I;
      if (e < NE && e < 1024) {
        float tu = time_uniq[e];
        int k0 = (int)floorf((tu - EPS_F) * 100.0f) - 2;
        if (k0 < 0) k0 = 0;
        while ((float)k0 * DT_F + EPS_F < tu) ++k0;
        gv = k0 - e;
      }
      pm = max(pm, gv);
      loc[j] = pm;
    }
    int tot = pm;
#pragma unroll
    for (int off = 1; off < 64; off <<= 1) {
      int v = __shfl_up(tot, off);
      if (lane >= off) tot = max(tot, v);
    }
    int excl = __shfl_up(tot, 1);
    if (lane == 0) excl = NEG_INF_I;
#pragma unroll
    for (int j = 0; j < 16; ++j)
      sStep[lane * 16 + j] = lane * 16 + j + max(loc[j], excl);
  }
  __syncthreads();   // init only

  // ---- ODE weights: load once, ANCHOR once (opaque def kills remat) ----
  const uint4* odeQ = (const uint4*)odeP;
  uint4 WR[8], WZ[8], WU[8];
#pragma unroll
  for (int q = 0; q < 8; ++q) {
    WR[q] = odeQ[(0 * 64 + lane) * 8 + q];
    WZ[q] = odeQ[(1 * 64 + lane) * 8 + q];
    WU[q] = odeQ[(2 * 64 + lane) * 8 + q];
  }
#pragma unroll
  for (int q = 0; q < 8; ++q) { ANCH4(WR[q]); ANCH4(WZ[q]); ANCH4(WU[q]); }

  const uint4* wihQ = (const uint4*)wihP;

  float xr = gx_b[lane], xz = gx_b[64 + lane], xh = gx_b[128 + lane];
  float crz_r = gb_bih[lane] + gb_bhh[lane];
  float crz_z = gb_bih[64 + lane] + gb_bhh[64 + lane];
  float bihn = gb_bih[128 + lane], bhhn = gb_bhh[128 + lane];
  ANCHF(xr); ANCHF(xz); ANCHF(xh); ANCHF(crz_r); ANCHF(crz_z);
  ANCHF(bihn); ANCHF(bhhn);

  // ---- h0 ----
  float h = 0.0f;
  if (alive) {
    float cacc = cov_b1[lane];
    for (int c = 0; c < COV; ++c)
      cacc = fmaf(covs[b * COV + c], cov_W1[lane * COV + c], cacc);
    float cl = fmaxf(cacc, 0.0f);
    float hacc = cov_b2[lane];
#pragma unroll
    for (int j = 0; j < 64; ++j)
      hacc = fmaf(rl(cl, j), cov_W2[lane * 64 + j], hacc);
    h = tanhf_fast(hacc);
  }
  sH16[wid][lane] = (f16)h;

  // ---- event pipeline (2-deep) ----
  int e_next = 0, s_next = 0x7fffffff, v_cur = 0, v_pipe = 0;
  float xf[8];
#pragma unroll
  for (int kk = 0; kk < 8; ++kk) xf[kk] = 0.0f;
  if (alive && NE > 0) {
    s_next = sStep[0];
    v_cur = evtab[b];
    if (v_cur > 0) {
      const float* xp = X + (long)(v_cur - 1) * IN;
#pragma unroll
      for (int kk = 0; kk < 8; ++kk) xf[kk] = (kk < IN) ? xp[kk] : 0.0f;
    }
    v_pipe = (NE > 1) ? evtab[B + b] : 0;
  } else if (NE > 0) {
    s_next = sStep[0];
  }

  const uint4* hq4 = (const uint4*)sH16[wid];
  const uint4* rq4 = (const uint4*)sRH16[wid];
  f16* hps = hp16 + (long)b * 64 + lane;
  const long rowstride = (long)B * 64;

#pragma unroll 1
  for (int k = 0; k < n_steps; ++k) {
    if (k == s_next) {                       // wave-uniform schedule
      if (v_cur > 0) {                       // this sample fires (wave-uniform)
        unsigned xp0 = packf16(xf[0], xf[1]), xp1 = packf16(xf[2], xf[3]);
        unsigned xp2 = packf16(xf[4], xf[5]), xp3 = packf16(xf[6], xf[7]);
        uint4 wxr = wihQ[lane], wxz = wihQ[64 + lane], wxn = wihQ[128 + lane];
        float ar = crz_r, az = crz_z, anh = bhhn, ani = bihn;
        ar = dot2(wxr.x, xp0, ar); ar = dot2(wxr.y, xp1, ar);
        ar = dot2(wxr.z, xp2, ar); ar = dot2(wxr.w, xp3, ar);
        az = dot2(wxz.x, xp0, az); az = dot2(wxz.y, xp1, az);
        az = dot2(wxz.z, xp2, az); az = dot2(wxz.w, xp3, az);
        ani = dot2(wxn.x, xp0, ani); ani = dot2(wxn.y, xp1, ani);
        ani = dot2(wxn.z, xp2, ani); ani = dot2(wxn.w, xp3, ani);
        float ar1 = 0.f, az1 = 0.f, an1 = 0.f;
#pragma unroll
        for (int q = 0; q < 8; ++q) {
          uint4 hh = hq4[q];
          int sw = ((q ^ (lane & 7)) << 2);
          uint4 br = *(const uint4*)&sBW[(0 * 64 + lane) * 32 + sw];
          uint4 bz = *(const uint4*)&sBW[(1 * 64 + lane) * 32 + sw];
          uint4 bn = *(const uint4*)&sBW[(2 * 64 + lane) * 32 + sw];
          ar  = dot2(br.x, hh.x, ar);   ar1 = dot2(br.y, hh.y, ar1);
          ar  = dot2(br.z, hh.z, ar);   ar1 = dot2(br.w, hh.w, ar1);
          az  = dot2(bz.x, hh.x, az);   az1 = dot2(bz.y, hh.y, az1);
          az  = dot2(bz.z, hh.z, az);   az1 = dot2(bz.w, hh.w, az1);
          anh = dot2(bn.x, hh.x, anh);  an1 = dot2(bn.y, hh.y, an1);
          anh = dot2(bn.z, hh.z, anh);  an1 = dot2(bn.w, hh.w, an1);
        }
        float r = sigm(ar + ar1);
        float z = sigm(az + az1);
        float n = tanhf_fast(ani + r * (anh + an1));
        h = (1.0f - z) * n + z * h;
        sH16[wid][lane] = (f16)h;
      }
      ++e_next;
      if (e_next < NE && e_next < 1024) {
        s_next = sStep[e_next];
        v_cur = v_pipe;
        if (v_cur > 0) {
          const float* xp = X + (long)(v_cur - 1) * IN;
#pragma unroll
          for (int kk = 0; kk < 8; ++kk) xf[kk] = (kk < IN) ? xp[kk] : 0.0f;
        }
        v_pipe = (e_next + 1 < NE) ? evtab[(long)(e_next + 1) * B + b] : 0;
      } else {
        s_next = 0x7fffffff;
        v_cur = 0;
      }
    }

    if (alive)
      hps[(long)k * rowstride] = (f16)h;     // h_rec (post-event, pre-ODE), f16

    // ---- phase A: r,z (anchored weights, h pairs from LDS) ----
    float ar0 = xr, ar1 = 0.f, ar2 = 0.f, ar3 = 0.f;
    float az0 = xz, az1 = 0.f, az2 = 0.f, az3 = 0.f;
#pragma unroll
    for (int q = 0; q < 8; ++q) {
      uint4 hp = hq4[q];
      ar0 = dot2(WR[q].x, hp.x, ar0); ar1 = dot2(WR[q].y, hp.y, ar1);
      ar2 = dot2(WR[q].z, hp.z, ar2); ar3 = dot2(WR[q].w, hp.w, ar3);
      az0 = dot2(WZ[q].x, hp.x, az0); az1 = dot2(WZ[q].y, hp.y, az1);
      az2 = dot2(WZ[q].z, hp.z, az2); az3 = dot2(WZ[q].w, hp.w, az3);
    }
    float r = sigm((ar0 + ar1) + (ar2 + ar3));
    float z = sigm((az0 + az1) + (az2 + az3));
    sRH16[wid][lane] = (f16)(r * h);

    // ---- phase B: u matvec (r*h broadcast) ----
    float au0 = xh, au1 = 0.f, au2 = 0.f, au3 = 0.f;
#pragma unroll
    for (int q = 0; q < 8; ++q) {
      uint4 rp = rq4[q];
      au0 = dot2(WU[q].x, rp.x, au0); au1 = dot2(WU[q].y, rp.y, au1);
      au2 = dot2(WU[q].z, rp.z, au2); au3 = dot2(WU[q].w, rp.w, au3);
    }
    float u = tanhf_fast((au0 + au1) + (au2 + au3));
    h = fmaf(DT_F * (1.0f - z), u - h, h);
    sH16[wid][lane] = (f16)h;
  }

  if (alive)
    hps[(long)n_steps * rowstride] = (f16)h;   // h_last
}

// MFMA head (verified R9): out[row] = relu(h[row] @ W1^T + b1) @ W2^T + b2.
__global__ __launch_bounds__(256, 4) void head_mfma_kernel(
    const f16* __restrict__ hp16, const f16* __restrict__ w1P,
    const float* __restrict__ b1, const float* __restrict__ W2,
    const float* __restrict__ b2, float* __restrict__ out, long nrows)
{
  const int wq = threadIdx.x >> 6, lane = threadIdx.x & 63;
  const int col = lane & 15;
  const long rowbase = ((long)blockIdx.x * 4 + wq) * 64;   // 64 rows per wave

  f16x8 Wf[8][2];
#pragma unroll
  for (int t = 0; t < 8; ++t)
#pragma unroll
    for (int kf = 0; kf < 2; ++kf)
      Wf[t][kf] = ((const f16x8*)w1P)[(2 * t + kf) * 64 + lane];

  float b1v[8], w2a[8], w2b[8];
#pragma unroll
  for (int t = 0; t < 8; ++t) {
    b1v[t] = b1[16 * t + col];
    w2a[t] = W2[16 * t + col];
    w2b[t] = W2[128 + 16 * t + col];
  }
  const float b20 = b2[0], b21 = b2[1];

#pragma unroll 1
  for (int g = 0; g < 4; ++g) {
    long row0 = rowbase + g * 16;
    long arow = row0 + col;
    f16x8 aH0 = {0, 0, 0, 0, 0, 0, 0, 0}, aH1 = aH0;
    if (arow < nrows) {
      const f16x8* ap = (const f16x8*)(hp16 + arow * 64);
      aH0 = ap[lane >> 4];
      aH1 = ap[(lane >> 4) + 4];
    }
    float p0[4] = {0.f, 0.f, 0.f, 0.f}, p1[4] = {0.f, 0.f, 0.f, 0.f};
#pragma unroll
    for (int t = 0; t < 8; ++t) {
      f32x4 c = {0.f, 0.f, 0.f, 0.f};
      c = MFMA16(aH0, Wf[t][0], c);
      c = MFMA16(aH1, Wf[t][1], c);
#pragma unroll
      for (int i = 0; i < 4; ++i) {
        float o = fmaxf(c[i] + b1v[t], 0.0f);
        p0[i] = fmaf(o, w2a[t], p0[i]);
        p1[i] = fmaf(o, w2b[t], p1[i]);
      }
    }
#pragma unroll
    for (int off = 1; off < 16; off <<= 1) {
#pragma unroll
      for (int i = 0; i < 4; ++i) {
        p0[i] += __shfl_xor(p0[i], off);
        p1[i] += __shfl_xor(p1[i], off);
      }
    }
    if (col == 0) {
#pragma unroll
      for (int i = 0; i < 4; ++i) {
        long row = row0 + (lane >> 4) * 4 + i;
        if (row < nrows) {
          out[row * 2 + 0] = p0[i] + b20;
          out[row * 2 + 1] = p1[i] + b21;
        }
      }
    }
  }
}

extern "C" void kernel_launch(void* const* d_in, const int* in_sizes, int n_in,
                              void* d_out, int out_size, void* d_ws, size_t ws_size,
                              hipStream_t stream) {
  const float* time_uniq  = (const float*)d_in[0];
  const int*   time_ptr   = (const int*)d_in[1];
  const float* X          = (const float*)d_in[2];
  const int*   sample_ids = (const int*)d_in[3];
  const float* covs       = (const float*)d_in[4];
  const float* cov_W1     = (const float*)d_in[6];
  const float* cov_b1     = (const float*)d_in[7];
  const float* cov_W2     = (const float*)d_in[8];
  const float* cov_b2     = (const float*)d_in[9];
  const float* gb_Wih     = (const float*)d_in[10];
  const float* gb_Whh     = (const float*)d_in[11];
  const float* gb_bih     = (const float*)d_in[12];
  const float* gb_bhh     = (const float*)d_in[13];
  const float* gx_b       = (const float*)d_in[15];
  const float* ghr_W      = (const float*)d_in[16];
  const float* ghz_W      = (const float*)d_in[17];
  const float* ghh_W      = (const float*)d_in[18];
  const float* out_W1     = (const float*)d_in[19];
  const float* out_b1     = (const float*)d_in[20];
  const float* out_W2     = (const float*)d_in[21];
  const float* out_b2     = (const float*)d_in[22];

  int NE   = in_sizes[0];
  int TOT  = in_sizes[3];
  int IN   = in_sizes[2] / TOT;
  int CH   = in_sizes[7];
  int COV  = in_sizes[6] / CH;
  int B    = in_sizes[4] / COV;
  int OUTD = in_sizes[22];
  int n_steps = out_size / (B * OUTD) - 1;
  int OPE  = TOT / NE;

  char* ws = (char*)d_ws;
  int* evtab = (int*)ws;
  size_t evbytes = (size_t)NE * (size_t)B * sizeof(int);
  size_t off1 = (evbytes + 255) & ~(size_t)255;
  unsigned* odeP = (unsigned*)(ws + off1);
  unsigned* bayP = odeP + 3 * 64 * 32;
  unsigned* wihP = bayP + 3 * 64 * 32;
  size_t off2 = off1 + (((3 * 64 * 32 * 2 + 3 * 64 * 4) * sizeof(unsigned) + 255) & ~(size_t)255);
  f16* w1P = (f16*)(ws + off2);
  size_t off3 = off2 + ((16 * 512 * sizeof(f16) + 255) & ~(size_t)255);
  f16* hp16 = (f16*)(ws + off3);

  hipMemsetAsync(evtab, 0, evbytes, stream);
  build_evtab_kernel<<<NE, 256, 0, stream>>>(sample_ids, time_ptr, evtab, B, OPE);
  pack_pairs_kernel<<<24, 256, 0, stream>>>(ghr_W, ghz_W, ghh_W, gb_Whh, gb_Wih,
                                            odeP, bayP, wihP, IN);
  pack_head_kernel<<<16, 64, 0, stream>>>(out_W1, w1P);
  evolve_kernel<<<(B + 3) / 4, 256, 0, stream>>>(
      time_uniq, X, covs, cov_W1, cov_b1, cov_W2, cov_b2,
      gb_bih, gb_bhh, gx_b, odeP, bayP, wihP,
      evtab, hp16, B, NE, n_steps, IN, COV);
  long nrows = (long)(n_steps + 1) * B;
  int hb = (int)((nrows + 255) / 256);
  head_mfma_kernel<<<hb, 256, 0, stream>>>(hp16, w1P, out_b1, out_W2, out_b2,
                                           (float*)d_out, nrows);
}

// Round 11
// 433.287 us; speedup vs baseline: 2.2028x; 1.0323x over previous
//
#include <hip/hip_runtime.h>

#define DT_F 0.01f
#define EPS_F 1e-5f
#define NEG_INF_I (-1073741824)

typedef _Float16 f16;
typedef _Float16 f16x2 __attribute__((ext_vector_type(2)));
typedef _Float16 f16x8 __attribute__((ext_vector_type(8)));
typedef float f32x4 __attribute__((ext_vector_type(4)));

#define MFMA16(a, b, c) __builtin_amdgcn_mfma_f32_16x16x32_f16((a), (b), (c), 0, 0, 0)

__device__ __forceinline__ float rl(float v, int l) {
  return __int_as_float(__builtin_amdgcn_readlane(__float_as_int(v), l));
}
__device__ __forceinline__ float sigm(float x) {
  float e = __builtin_amdgcn_exp2f(-1.442695041f * x);
  return __builtin_amdgcn_rcpf(1.0f + e);
}
__device__ __forceinline__ float tanhf_fast(float x) {
  float e = __builtin_amdgcn_exp2f(2.885390082f * x);
  return fmaf(-2.0f, __builtin_amdgcn_rcpf(e + 1.0f), 1.0f);
}
__device__ __forceinline__ float dot2(unsigned w, unsigned h, float acc) {
  return __builtin_amdgcn_fdot2(__builtin_bit_cast(f16x2, w),
                                __builtin_bit_cast(f16x2, h), acc, false);
}
__device__ __forceinline__ unsigned packf16(float a, float b) {
  return __builtin_bit_cast(unsigned, __builtin_amdgcn_cvt_pkrtz(a, b));
}
#define ANCH4(v) asm volatile("" : "+v"((v).x), "+v"((v).y), "+v"((v).z), "+v"((v).w))

// evtab[k*B + sid] = (last obs index in event k's window with sample_ids==sid) + 1, or 0.
__global__ void build_evtab_kernel(const int* __restrict__ sample_ids,
                                   const int* __restrict__ time_ptr,
                                   int* __restrict__ evtab, int B, int ope) {
  int k = blockIdx.x;
  int base = time_ptr[k];
  for (int t = threadIdx.x; t < ope; t += blockDim.x) {
    int obs = base + t;
    int sid = sample_ids[obs];
    atomicMax(&evtab[k * B + sid], obs + 1);   // last occurrence wins
  }
}

// f16-pair packing (verified R7)
__global__ void pack_pairs_kernel(const float* __restrict__ ghr,
                                  const float* __restrict__ ghz,
                                  const float* __restrict__ ghh,
                                  const float* __restrict__ gbWhh,
                                  const float* __restrict__ gbWih,
                                  unsigned* __restrict__ odeP,
                                  unsigned* __restrict__ bayP,
                                  unsigned* __restrict__ wihP, int IN) {
  int idx = blockIdx.x * 256 + threadIdx.x;
  if (idx < 3 * 64 * 32) {
    int p = idx & 31, r = idx >> 5;
    int g = r >> 6, i = r & 63;
    const float* src = (g == 0) ? ghr : ((g == 1) ? ghz : ghh);
    odeP[idx] = packf16(src[i * 64 + 2 * p], src[i * 64 + 2 * p + 1]);
    bayP[idx] = packf16(gbWhh[r * 64 + 2 * p], gbWhh[r * 64 + 2 * p + 1]);
  }
  if (idx < 3 * 64 * 4) {
    int p = idx & 3, r = idx >> 2;
    float a = (2 * p < IN) ? gbWih[r * IN + 2 * p] : 0.0f;
    float b = (2 * p + 1 < IN) ? gbWih[r * IN + 2 * p + 1] : 0.0f;
    wihP[idx] = packf16(a, b);
  }
}

// W1 -> MFMA B-fragments (layout HW-verified in R5)
__global__ void pack_head_kernel(const float* __restrict__ W1, f16* __restrict__ w1P) {
  int f = blockIdx.x;       // 0..15
  int l = threadIdx.x;      // 0..63
  int t = f >> 1, kf = f & 1;
  int n = 16 * t + (l & 15);
  for (int j = 0; j < 8; ++j) {
    int k = 8 * (l >> 4) + j + 32 * kf;
    w1P[f * 512 + l * 8 + j] = (f16)W1[n * 64 + k];
  }
}

// ONE SAMPLE per 128-thread block = 2 waves/SIMD across the chip.
// wave0: state master (z + u + events/Bayes + stores). wave1: r producer.
// 2 barriers/step (+1 on firing steps). evtab column in LDS.
__global__ __launch_bounds__(128, 2) void evolve_kernel(
    const float* __restrict__ time_uniq,
    const float* __restrict__ X,
    const float* __restrict__ covs,
    const float* __restrict__ cov_W1, const float* __restrict__ cov_b1,
    const float* __restrict__ cov_W2, const float* __restrict__ cov_b2,
    const float* __restrict__ gb_bih, const float* __restrict__ gb_bhh,
    const float* __restrict__ gx_b,
    const unsigned* __restrict__ odeP, const unsigned* __restrict__ bayP,
    const unsigned* __restrict__ wihP,
    const int* __restrict__ evtab,
    f16* __restrict__ hp16,
    int B, int NE, int n_steps, int IN, int COV)
{
  __shared__ unsigned sBW[3 * 64 * 32];            // Bayes pairs, swizzled (24KB)
  __shared__ int sStep[1024];                      // event -> grid step (4KB)
  __shared__ int sEvt[1024];                       // this sample's evtab col (4KB)
  __shared__ __align__(16) f16 sHimg[64];          // h image (f16)
  __shared__ __align__(16) f16 sRHimg[64];         // r*h image (f16)

  const int tid = threadIdx.x;
  const int wid = tid >> 6, lane = tid & 63;
  const int b = blockIdx.x;
  const int necap = (NE < 1024) ? NE : 1024;

  for (int idx = tid; idx < 3 * 64 * 32; idx += 128) {
    int c = idx & 31, r = idx >> 5;
    int i = r & 63, s = c >> 2;
    sBW[r * 32 + (((s ^ (i & 7)) << 2) | (c & 3))] = bayP[idx];
  }
  for (int e = tid; e < necap; e += 128)
    sEvt[e] = evtab[(long)e * B + b];
  if (wid == 0) {     // wave-parallel prefix-max event schedule (verified R6/R7)
    int pm = NEG_INF_I;
    int loc[16];
#pragma unroll
    for (int j = 0; j < 16; ++j) {
      int e = lane * 16 + j;
      int gv = NEG_INF_I;
      if (e < necap) {
        float tu = time_uniq[e];
        int k0 = (int)floorf((tu - EPS_F) * 100.0f) - 2;
        if (k0 < 0) k0 = 0;
        while ((float)k0 * DT_F + EPS_F < tu) ++k0;
        gv = k0 - e;
      }
      pm = max(pm, gv);
      loc[j] = pm;
    }
    int tot = pm;
#pragma unroll
    for (int off = 1; off < 64; off <<= 1) {
      int v = __shfl_up(tot, off);
      if (lane >= off) tot = max(tot, v);
    }
    int excl = __shfl_up(tot, 1);
    if (lane == 0) excl = NEG_INF_I;
#pragma unroll
    for (int j = 0; j < 16; ++j)
      sStep[lane * 16 + j] = lane * 16 + j + max(loc[j], excl);
  }
  if (wid == 0) {   // ---- h0 on wave0 ----
    float cacc = cov_b1[lane];
    for (int c = 0; c < COV; ++c)
      cacc = fmaf(covs[b * COV + c], cov_W1[lane * COV + c], cacc);
    float cl = fmaxf(cacc, 0.0f);
    float hacc = cov_b2[lane];
#pragma unroll
    for (int j = 0; j < 64; ++j)
      hacc = fmaf(rl(cl, j), cov_W2[lane * 64 + j], hacc);
    sHimg[lane] = (f16)tanhf_fast(hacc);
  }
  __syncthreads();   // init complete

  const uint4* odeQ = (const uint4*)odeP;
  const uint4* hq4 = (const uint4*)sHimg;
  const uint4* rq4 = (const uint4*)sRHimg;

  if (wid == 0) {
    // ================= WAVE 0: state master =================
    uint4 WZ[8], WU[8];
#pragma unroll
    for (int q = 0; q < 8; ++q) {
      WZ[q] = odeQ[(1 * 64 + lane) * 8 + q];
      WU[q] = odeQ[(2 * 64 + lane) * 8 + q];
    }
#pragma unroll
    for (int q = 0; q < 8; ++q) { ANCH4(WZ[q]); ANCH4(WU[q]); }
    const uint4* wihQ = (const uint4*)wihP;

    const float xz = gx_b[64 + lane], xh = gx_b[128 + lane];
    const float crz_r = gb_bih[lane] + gb_bhh[lane];
    const float crz_z = gb_bih[64 + lane] + gb_bhh[64 + lane];
    const float bihn = gb_bih[128 + lane], bhhn = gb_bhh[128 + lane];

    float h = (float)sHimg[lane];
    f16* hps = hp16 + (long)b * 64 + lane;
    const long rowstride = (long)B * 64;

    int e_next = 0, s_next = 0x7fffffff, v_cur = 0, v_pipe = 0;
    float xf[8];
#pragma unroll
    for (int kk = 0; kk < 8; ++kk) xf[kk] = 0.0f;
    if (necap > 0) {
      s_next = sStep[0];
      v_cur = sEvt[0];
      if (v_cur > 0) {
        const float* xp = X + (long)(v_cur - 1) * IN;
#pragma unroll
        for (int kk = 0; kk < 8; ++kk) xf[kk] = (kk < IN) ? xp[kk] : 0.0f;
      }
      v_pipe = (necap > 1) ? sEvt[1] : 0;
    }

#pragma unroll 1
    for (int k = 0; k < n_steps; ++k) {
      if (k == s_next) {
        const bool fire = (v_cur > 0);
        if (fire) {
          unsigned xp0 = packf16(xf[0], xf[1]), xp1 = packf16(xf[2], xf[3]);
          unsigned xp2 = packf16(xf[4], xf[5]), xp3 = packf16(xf[6], xf[7]);
          uint4 wxr = wihQ[lane], wxz = wihQ[64 + lane], wxn = wihQ[128 + lane];
          float ar = crz_r, az = crz_z, anh = bhhn, ani = bihn;
          ar = dot2(wxr.x, xp0, ar); ar = dot2(wxr.y, xp1, ar);
          ar = dot2(wxr.z, xp2, ar); ar = dot2(wxr.w, xp3, ar);
          az = dot2(wxz.x, xp0, az); az = dot2(wxz.y, xp1, az);
          az = dot2(wxz.z, xp2, az); az = dot2(wxz.w, xp3, az);
          ani = dot2(wxn.x, xp0, ani); ani = dot2(wxn.y, xp1, ani);
          ani = dot2(wxn.z, xp2, ani); ani = dot2(wxn.w, xp3, ani);
          float ar1 = 0.f, az1 = 0.f, an1 = 0.f;
#pragma unroll
          for (int q = 0; q < 8; ++q) {
            uint4 hh = hq4[q];
            int sw = ((q ^ (lane & 7)) << 2);
            uint4 br = *(const uint4*)&sBW[(0 * 64 + lane) * 32 + sw];
            uint4 bz = *(const uint4*)&sBW[(1 * 64 + lane) * 32 + sw];
            uint4 bn = *(const uint4*)&sBW[(2 * 64 + lane) * 32 + sw];
            ar  = dot2(br.x, hh.x, ar);   ar1 = dot2(br.y, hh.y, ar1);
            ar  = dot2(br.z, hh.z, ar);   ar1 = dot2(br.w, hh.w, ar1);
            az  = dot2(bz.x, hh.x, az);   az1 = dot2(bz.y, hh.y, az1);
            az  = dot2(bz.z, hh.z, az);   az1 = dot2(bz.w, hh.w, az1);
            anh = dot2(bn.x, hh.x, anh);  an1 = dot2(bn.y, hh.y, an1);
            anh = dot2(bn.z, hh.z, anh);  an1 = dot2(bn.w, hh.w, an1);
          }
          float r = sigm(ar + ar1);
          float z = sigm(az + az1);
          float n = tanhf_fast(ani + r * (anh + an1));
          h = (1.0f - z) * n + z * h;
          sHimg[lane] = (f16)h;
        }
        ++e_next;
        if (e_next < necap) {
          s_next = sStep[e_next];
          v_cur = v_pipe;
          if (v_cur > 0) {
            const float* xp = X + (long)(v_cur - 1) * IN;
#pragma unroll
            for (int kk = 0; kk < 8; ++kk) xf[kk] = (kk < IN) ? xp[kk] : 0.0f;
          }
          v_pipe = (e_next + 1 < necap) ? sEvt[e_next + 1] : 0;
        } else {
          s_next = 0x7fffffff;
          v_cur = 0;
        }
        if (fire) __syncthreads();           // event image ready
      }

      hps[(long)k * rowstride] = (f16)h;     // h_rec (post-event, pre-ODE)

      // z gate
      float az0 = xz, az1 = 0.f, az2 = 0.f, az3 = 0.f;
#pragma unroll
      for (int q = 0; q < 8; ++q) {
        uint4 hp = hq4[q];
        az0 = dot2(WZ[q].x, hp.x, az0); az1 = dot2(WZ[q].y, hp.y, az1);
        az2 = dot2(WZ[q].z, hp.z, az2); az3 = dot2(WZ[q].w, hp.w, az3);
      }
      float z = sigm((az0 + az1) + (az2 + az3));
      __syncthreads();                       // B1: rh image ready

      float au0 = xh, au1 = 0.f, au2 = 0.f, au3 = 0.f;
#pragma unroll
      for (int q = 0; q < 8; ++q) {
        uint4 rp = rq4[q];
        au0 = dot2(WU[q].x, rp.x, au0); au1 = dot2(WU[q].y, rp.y, au1);
        au2 = dot2(WU[q].z, rp.z, au2); au3 = dot2(WU[q].w, rp.w, au3);
      }
      float u = tanhf_fast((au0 + au1) + (au2 + au3));
      h = fmaf(DT_F * (1.0f - z), u - h, h);
      sHimg[lane] = (f16)h;
      __syncthreads();                       // B2: h image ready
    }
    hps[(long)n_steps * rowstride] = (f16)h; // h_last
  } else {
    // ================= WAVE 1: r producer =================
    uint4 WR[8];
#pragma unroll
    for (int q = 0; q < 8; ++q) WR[q] = odeQ[(0 * 64 + lane) * 8 + q];
#pragma unroll
    for (int q = 0; q < 8; ++q) ANCH4(WR[q]);
    const float xr = gx_b[lane];

    int e_next = 0, s_next = 0x7fffffff, v_cur = 0, v_pipe = 0;
    if (necap > 0) {
      s_next = sStep[0];
      v_cur = sEvt[0];
      v_pipe = (necap > 1) ? sEvt[1] : 0;
    }

#pragma unroll 1
    for (int k = 0; k < n_steps; ++k) {
      if (k == s_next) {
        const bool fire = (v_cur > 0);
        ++e_next;
        if (e_next < necap) {
          s_next = sStep[e_next];
          v_cur = v_pipe;
          v_pipe = (e_next + 1 < necap) ? sEvt[e_next + 1] : 0;
        } else {
          s_next = 0x7fffffff;
          v_cur = 0;
        }
        if (fire) __syncthreads();           // event image ready
      }

      // r gate
      float ar0 = xr, ar1 = 0.f, ar2 = 0.f, ar3 = 0.f;
#pragma unroll
      for (int q = 0; q < 8; ++q) {
        uint4 hp = hq4[q];
        ar0 = dot2(WR[q].x, hp.x, ar0); ar1 = dot2(WR[q].y, hp.y, ar1);
        ar2 = dot2(WR[q].z, hp.z, ar2); ar3 = dot2(WR[q].w, hp.w, ar3);
      }
      float r = sigm((ar0 + ar1) + (ar2 + ar3));
      float hf = (float)sHimg[lane];
      sRHimg[lane] = (f16)(r * hf);
      __syncthreads();                       // B1: rh image ready
      __syncthreads();                       // B2: h image ready
    }
  }
}

// MFMA head (verified R9): out[row] = relu(h[row] @ W1^T + b1) @ W2^T + b2.
__global__ __launch_bounds__(256, 4) void head_mfma_kernel(
    const f16* __restrict__ hp16, const f16* __restrict__ w1P,
    const float* __restrict__ b1, const float* __restrict__ W2,
    const float* __restrict__ b2, float* __restrict__ out, long nrows)
{
  const int wq = threadIdx.x >> 6, lane = threadIdx.x & 63;
  const int col = lane & 15;
  const long rowbase = ((long)blockIdx.x * 4 + wq) * 64;   // 64 rows per wave

  f16x8 Wf[8][2];
#pragma unroll
  for (int t = 0; t < 8; ++t)
#pragma unroll
    for (int kf = 0; kf < 2; ++kf)
      Wf[t][kf] = ((const f16x8*)w1P)[(2 * t + kf) * 64 + lane];

  float b1v[8], w2a[8], w2b[8];
#pragma unroll
  for (int t = 0; t < 8; ++t) {
    b1v[t] = b1[16 * t + col];
    w2a[t] = W2[16 * t + col];
    w2b[t] = W2[128 + 16 * t + col];
  }
  const float b20 = b2[0], b21 = b2[1];

#pragma unroll 1
  for (int g = 0; g < 4; ++g) {
    long row0 = rowbase + g * 16;
    long arow = row0 + col;
    f16x8 aH0 = {0, 0, 0, 0, 0, 0, 0, 0}, aH1 = aH0;
    if (arow < nrows) {
      const f16x8* ap = (const f16x8*)(hp16 + arow * 64);
      aH0 = ap[lane >> 4];
      aH1 = ap[(lane >> 4) + 4];
    }
    float p0[4] = {0.f, 0.f, 0.f, 0.f}, p1[4] = {0.f, 0.f, 0.f, 0.f};
#pragma unroll
    for (int t = 0; t < 8; ++t) {
      f32x4 c = {0.f, 0.f, 0.f, 0.f};
      c = MFMA16(aH0, Wf[t][0], c);
      c = MFMA16(aH1, Wf[t][1], c);
#pragma unroll
      for (int i = 0; i < 4; ++i) {
        float o = fmaxf(c[i] + b1v[t], 0.0f);
        p0[i] = fmaf(o, w2a[t], p0[i]);
        p1[i] = fmaf(o, w2b[t], p1[i]);
      }
    }
#pragma unroll
    for (int off = 1; off < 16; off <<= 1) {
#pragma unroll
      for (int i = 0; i < 4; ++i) {
        p0[i] += __shfl_xor(p0[i], off);
        p1[i] += __shfl_xor(p1[i], off);
      }
    }
    if (col == 0) {
#pragma unroll
      for (int i = 0; i < 4; ++i) {
        long row = row0 + (lane >> 4) * 4 + i;
        if (row < nrows) {
          out[row * 2 + 0] = p0[i] + b20;
          out[row * 2 + 1] = p1[i] + b21;
        }
      }
    }
  }
}

extern "C" void kernel_launch(void* const* d_in, const int* in_sizes, int n_in,
                              void* d_out, int out_size, void* d_ws, size_t ws_size,
                              hipStream_t stream) {
  const float* time_uniq  = (const float*)d_in[0];
  const int*   time_ptr   = (const int*)d_in[1];
  const float* X          = (const float*)d_in[2];
  const int*   sample_ids = (const int*)d_in[3];
  const float* covs       = (const float*)d_in[4];
  const float* cov_W1     = (const float*)d_in[6];
  const float* cov_b1     = (const float*)d_in[7];
  const float* cov_W2     = (const float*)d_in[8];
  const float* cov_b2     = (const float*)d_in[9];
  const float* gb_Wih     = (const float*)d_in[10];
  const float* gb_Whh     = (const float*)d_in[11];
  const float* gb_bih     = (const float*)d_in[12];
  const float* gb_bhh     = (const float*)d_in[13];
  const float* gx_b       = (const float*)d_in[15];
  const float* ghr_W      = (const float*)d_in[16];
  const float* ghz_W      = (const float*)d_in[17];
  const float* ghh_W      = (const float*)d_in[18];
  const float* out_W1     = (const float*)d_in[19];
  const float* out_b1     = (const float*)d_in[20];
  const float* out_W2     = (const float*)d_in[21];
  const float* out_b2     = (const float*)d_in[22];

  int NE   = in_sizes[0];
  int TOT  = in_sizes[3];
  int IN   = in_sizes[2] / TOT;
  int CH   = in_sizes[7];
  int COV  = in_sizes[6] / CH;
  int B    = in_sizes[4] / COV;
  int OUTD = in_sizes[22];
  int n_steps = out_size / (B * OUTD) - 1;
  int OPE  = TOT / NE;

  char* ws = (char*)d_ws;
  int* evtab = (int*)ws;
  size_t evbytes = (size_t)NE * (size_t)B * sizeof(int);
  size_t off1 = (evbytes + 255) & ~(size_t)255;
  unsigned* odeP = (unsigned*)(ws + off1);
  unsigned* bayP = odeP + 3 * 64 * 32;
  unsigned* wihP = bayP + 3 * 64 * 32;
  size_t off2 = off1 + (((3 * 64 * 32 * 2 + 3 * 64 * 4) * sizeof(unsigned) + 255) & ~(size_t)255);
  f16* w1P = (f16*)(ws + off2);
  size_t off3 = off2 + ((16 * 512 * sizeof(f16) + 255) & ~(size_t)255);
  f16* hp16 = (f16*)(ws + off3);

  hipMemsetAsync(evtab, 0, evbytes, stream);
  build_evtab_kernel<<<NE, 256, 0, stream>>>(sample_ids, time_ptr, evtab, B, OPE);
  pack_pairs_kernel<<<24, 256, 0, stream>>>(ghr_W, ghz_W, ghh_W, gb_Whh, gb_Wih,
                                            odeP, bayP, wihP, IN);
  pack_head_kernel<<<16, 64, 0, stream>>>(out_W1, w1P);
  evolve_kernel<<<B, 128, 0, stream>>>(
      time_uniq, X, covs, cov_W1, cov_b1, cov_W2, cov_b2,
      gb_bih, gb_bhh, gx_b, odeP, bayP, wihP,
      evtab, hp16, B, NE, n_steps, IN, COV);
  long nrows = (long)(n_steps + 1) * B;
  int hb = (int)((nrows + 255) / 256);
  head_mfma_kernel<<<hb, 256, 0, stream>>>(hp16, w1P, out_b1, out_W2, out_b2,
                                           (float*)d_out, nrows);
}

// Round 12
// 432.230 us; speedup vs baseline: 2.2082x; 1.0024x over previous
//
#include <hip/hip_runtime.h>

#define DT_F 0.01f
#define EPS_F 1e-5f
#define NEG_INF_I (-1073741824)
#define NEC 1024   // padded event capacity (stride of evtabT rows)

typedef _Float16 f16;
typedef _Float16 f16x2 __attribute__((ext_vector_type(2)));
typedef _Float16 f16x8 __attribute__((ext_vector_type(8)));
typedef float f32x4 __attribute__((ext_vector_type(4)));

#define MFMA16(a, b, c) __builtin_amdgcn_mfma_f32_16x16x32_f16((a), (b), (c), 0, 0, 0)

__device__ __forceinline__ float rl(float v, int l) {
  return __int_as_float(__builtin_amdgcn_readlane(__float_as_int(v), l));
}
__device__ __forceinline__ float sigm(float x) {
  float e = __builtin_amdgcn_exp2f(-1.442695041f * x);
  return __builtin_amdgcn_rcpf(1.0f + e);
}
__device__ __forceinline__ float tanhf_fast(float x) {
  float e = __builtin_amdgcn_exp2f(2.885390082f * x);
  return fmaf(-2.0f, __builtin_amdgcn_rcpf(e + 1.0f), 1.0f);
}
__device__ __forceinline__ float dot2(unsigned w, unsigned h, float acc) {
  return __builtin_amdgcn_fdot2(__builtin_bit_cast(f16x2, w),
                                __builtin_bit_cast(f16x2, h), acc, false);
}
__device__ __forceinline__ unsigned packf16(float a, float b) {
  return __builtin_bit_cast(unsigned, __builtin_amdgcn_cvt_pkrtz(a, b));
}
#define ANCH4(v) asm volatile("" : "+v"((v).x), "+v"((v).y), "+v"((v).z), "+v"((v).w))

// evtabT[sid*NEC + k] = (last obs index in event k's window with sample_ids==sid)+1, or 0.
// TRANSPOSED layout: per-sample event row is contiguous (coalesced staging).
__global__ void build_evtab_kernel(const int* __restrict__ sample_ids,
                                   const int* __restrict__ time_ptr,
                                   int* __restrict__ evtabT, int B, int ope) {
  int k = blockIdx.x;
  int base = time_ptr[k];
  for (int t = threadIdx.x; t < ope; t += blockDim.x) {
    int obs = base + t;
    int sid = sample_ids[obs];
    atomicMax(&evtabT[(long)sid * NEC + k], obs + 1);   // last occurrence wins
  }
}

// f16-pair packing (verified R7)
__global__ void pack_pairs_kernel(const float* __restrict__ ghr,
                                  const float* __restrict__ ghz,
                                  const float* __restrict__ ghh,
                                  const float* __restrict__ gbWhh,
                                  const float* __restrict__ gbWih,
                                  unsigned* __restrict__ odeP,
                                  unsigned* __restrict__ bayP,
                                  unsigned* __restrict__ wihP, int IN) {
  int idx = blockIdx.x * 256 + threadIdx.x;
  if (idx < 3 * 64 * 32) {
    int p = idx & 31, r = idx >> 5;
    int g = r >> 6, i = r & 63;
    const float* src = (g == 0) ? ghr : ((g == 1) ? ghz : ghh);
    odeP[idx] = packf16(src[i * 64 + 2 * p], src[i * 64 + 2 * p + 1]);
    bayP[idx] = packf16(gbWhh[r * 64 + 2 * p], gbWhh[r * 64 + 2 * p + 1]);
  }
  if (idx < 3 * 64 * 4) {
    int p = idx & 3, r = idx >> 2;
    float a = (2 * p < IN) ? gbWih[r * IN + 2 * p] : 0.0f;
    float b = (2 * p + 1 < IN) ? gbWih[r * IN + 2 * p + 1] : 0.0f;
    wihP[idx] = packf16(a, b);
  }
}

// W1 -> MFMA B-fragments (layout HW-verified in R5)
__global__ void pack_head_kernel(const float* __restrict__ W1, f16* __restrict__ w1P) {
  int f = blockIdx.x;       // 0..15
  int l = threadIdx.x;      // 0..63
  int t = f >> 1, kf = f & 1;
  int n = 16 * t + (l & 15);
  for (int j = 0; j < 8; ++j) {
    int k = 8 * (l >> 4) + j + 32 * kf;
    w1P[f * 512 + l * 8 + j] = (f16)W1[n * 64 + k];
  }
}

// ONE SAMPLE per 128-thread block = 2048 waves. wave0: state master (events,
// z, u, h update). wave1: r producer + ALL hpath stores. 2 barriers/step.
__global__ __launch_bounds__(128, 2) void evolve_kernel(
    const float* __restrict__ time_uniq,
    const float* __restrict__ X,
    const float* __restrict__ covs,
    const float* __restrict__ cov_W1, const float* __restrict__ cov_b1,
    const float* __restrict__ cov_W2, const float* __restrict__ cov_b2,
    const float* __restrict__ gb_bih, const float* __restrict__ gb_bhh,
    const float* __restrict__ gx_b,
    const unsigned* __restrict__ odeP, const unsigned* __restrict__ bayP,
    const unsigned* __restrict__ wihP,
    const int* __restrict__ evtabT,
    f16* __restrict__ hp16,
    int B, int NE, int n_steps, int IN, int COV)
{
  __shared__ unsigned sBW[3 * 64 * 32];            // Bayes pairs, swizzled (24KB)
  __shared__ int sStep[1024];                      // event -> grid step (4KB)
  __shared__ int sEvt[1024];                       // this sample's event row (4KB)
  __shared__ __align__(16) f16 sHimg[64];          // h image (f16)
  __shared__ __align__(16) f16 sRHimg[64];         // r*h image (f16)

  const int tid = threadIdx.x;
  const int wid = tid >> 6, lane = tid & 63;
  const int b = blockIdx.x;
  const int necap = (NE < NEC) ? NE : NEC;

  for (int idx = tid; idx < 3 * 64 * 32; idx += 128) {
    int c = idx & 31, r = idx >> 5;
    int i = r & 63, s = c >> 2;
    sBW[r * 32 + (((s ^ (i & 7)) << 2) | (c & 3))] = bayP[idx];
  }
  // coalesced event-row staging (evtabT row is contiguous)
  for (int e = tid; e < necap; e += 128)
    sEvt[e] = evtabT[(long)b * NEC + e];
  if (wid == 0) {     // wave-parallel prefix-max event schedule (verified R6/R7)
    int pm = NEG_INF_I;
    int loc[16];
#pragma unroll
    for (int j = 0; j < 16; ++j) {
      int e = lane * 16 + j;
      int gv = NEG_INF_I;
      if (e < necap) {
        float tu = time_uniq[e];
        int k0 = (int)floorf((tu - EPS_F) * 100.0f) - 2;
        if (k0 < 0) k0 = 0;
        while ((float)k0 * DT_F + EPS_F < tu) ++k0;
        gv = k0 - e;
      }
      pm = max(pm, gv);
      loc[j] = pm;
    }
    int tot = pm;
#pragma unroll
    for (int off = 1; off < 64; off <<= 1) {
      int v = __shfl_up(tot, off);
      if (lane >= off) tot = max(tot, v);
    }
    int excl = __shfl_up(tot, 1);
    if (lane == 0) excl = NEG_INF_I;
#pragma unroll
    for (int j = 0; j < 16; ++j)
      sStep[lane * 16 + j] = lane * 16 + j + max(loc[j], excl);
  }
  if (wid == 0) {   // ---- h0 on wave0 ----
    float cacc = cov_b1[lane];
    for (int c = 0; c < COV; ++c)
      cacc = fmaf(covs[b * COV + c], cov_W1[lane * COV + c], cacc);
    float cl = fmaxf(cacc, 0.0f);
    float hacc = cov_b2[lane];
#pragma unroll
    for (int j = 0; j < 64; ++j)
      hacc = fmaf(rl(cl, j), cov_W2[lane * 64 + j], hacc);
    sHimg[lane] = (f16)tanhf_fast(hacc);
  }
  __syncthreads();   // init complete

  const uint4* odeQ = (const uint4*)odeP;
  const uint4* hq4 = (const uint4*)sHimg;
  const uint4* rq4 = (const uint4*)sRHimg;

  if (wid == 0) {
    // ================= WAVE 0: state master (no global stores) =================
    uint4 WZ[8], WU[8];
#pragma unroll
    for (int q = 0; q < 8; ++q) {
      WZ[q] = odeQ[(1 * 64 + lane) * 8 + q];
      WU[q] = odeQ[(2 * 64 + lane) * 8 + q];
    }
#pragma unroll
    for (int q = 0; q < 8; ++q) { ANCH4(WZ[q]); ANCH4(WU[q]); }
    const uint4* wihQ = (const uint4*)wihP;

    const float xz = gx_b[64 + lane], xh = gx_b[128 + lane];
    const float crz_r = gb_bih[lane] + gb_bhh[lane];
    const float crz_z = gb_bih[64 + lane] + gb_bhh[64 + lane];
    const float bihn = gb_bih[128 + lane], bhhn = gb_bhh[128 + lane];

    float h = (float)sHimg[lane];

    int e_next = 0, s_next = 0x7fffffff, v_cur = 0, v_pipe = 0;
    float xf[8];
#pragma unroll
    for (int kk = 0; kk < 8; ++kk) xf[kk] = 0.0f;
    if (necap > 0) {
      s_next = sStep[0];
      v_cur = sEvt[0];
      if (v_cur > 0) {
        const float* xp = X + (long)(v_cur - 1) * IN;
#pragma unroll
        for (int kk = 0; kk < 8; ++kk) xf[kk] = (kk < IN) ? xp[kk] : 0.0f;
      }
      v_pipe = (necap > 1) ? sEvt[1] : 0;
    }

#pragma unroll 1
    for (int k = 0; k < n_steps; ++k) {
      if (k == s_next) {
        const bool fire = (v_cur > 0);
        if (fire) {
          unsigned xp0 = packf16(xf[0], xf[1]), xp1 = packf16(xf[2], xf[3]);
          unsigned xp2 = packf16(xf[4], xf[5]), xp3 = packf16(xf[6], xf[7]);
          uint4 wxr = wihQ[lane], wxz = wihQ[64 + lane], wxn = wihQ[128 + lane];
          float ar = crz_r, az = crz_z, anh = bhhn, ani = bihn;
          ar = dot2(wxr.x, xp0, ar); ar = dot2(wxr.y, xp1, ar);
          ar = dot2(wxr.z, xp2, ar); ar = dot2(wxr.w, xp3, ar);
          az = dot2(wxz.x, xp0, az); az = dot2(wxz.y, xp1, az);
          az = dot2(wxz.z, xp2, az); az = dot2(wxz.w, xp3, az);
          ani = dot2(wxn.x, xp0, ani); ani = dot2(wxn.y, xp1, ani);
          ani = dot2(wxn.z, xp2, ani); ani = dot2(wxn.w, xp3, ani);
          float ar1 = 0.f, az1 = 0.f, an1 = 0.f;
#pragma unroll
          for (int q = 0; q < 8; ++q) {
            uint4 hh = hq4[q];
            int sw = ((q ^ (lane & 7)) << 2);
            uint4 br = *(const uint4*)&sBW[(0 * 64 + lane) * 32 + sw];
            uint4 bz = *(const uint4*)&sBW[(1 * 64 + lane) * 32 + sw];
            uint4 bn = *(const uint4*)&sBW[(2 * 64 + lane) * 32 + sw];
            ar  = dot2(br.x, hh.x, ar);   ar1 = dot2(br.y, hh.y, ar1);
            ar  = dot2(br.z, hh.z, ar);   ar1 = dot2(br.w, hh.w, ar1);
            az  = dot2(bz.x, hh.x, az);   az1 = dot2(bz.y, hh.y, az1);
            az  = dot2(bz.z, hh.z, az);   az1 = dot2(bz.w, hh.w, az1);
            anh = dot2(bn.x, hh.x, anh);  an1 = dot2(bn.y, hh.y, an1);
            anh = dot2(bn.z, hh.z, anh);  an1 = dot2(bn.w, hh.w, an1);
          }
          float r = sigm(ar + ar1);
          float z = sigm(az + az1);
          float n = tanhf_fast(ani + r * (anh + an1));
          h = (1.0f - z) * n + z * h;
          sHimg[lane] = (f16)h;
        }
        ++e_next;
        if (e_next < necap) {
          s_next = sStep[e_next];
          v_cur = v_pipe;
          if (v_cur > 0) {
            const float* xp = X + (long)(v_cur - 1) * IN;
#pragma unroll
            for (int kk = 0; kk < 8; ++kk) xf[kk] = (kk < IN) ? xp[kk] : 0.0f;
          }
          v_pipe = (e_next + 1 < necap) ? sEvt[e_next + 1] : 0;
        } else {
          s_next = 0x7fffffff;
          v_cur = 0;
        }
        if (fire) __syncthreads();           // event image ready
      }

      // z gate
      float az0 = xz, az1 = 0.f, az2 = 0.f, az3 = 0.f;
#pragma unroll
      for (int q = 0; q < 8; ++q) {
        uint4 hp = hq4[q];
        az0 = dot2(WZ[q].x, hp.x, az0); az1 = dot2(WZ[q].y, hp.y, az1);
        az2 = dot2(WZ[q].z, hp.z, az2); az3 = dot2(WZ[q].w, hp.w, az3);
      }
      float z = sigm((az0 + az1) + (az2 + az3));
      __syncthreads();                       // B1: rh image ready

      float au0 = xh, au1 = 0.f, au2 = 0.f, au3 = 0.f;
#pragma unroll
      for (int q = 0; q < 8; ++q) {
        uint4 rp = rq4[q];
        au0 = dot2(WU[q].x, rp.x, au0); au1 = dot2(WU[q].y, rp.y, au1);
        au2 = dot2(WU[q].z, rp.z, au2); au3 = dot2(WU[q].w, rp.w, au3);
      }
      float u = tanhf_fast((au0 + au1) + (au2 + au3));
      h = fmaf(DT_F * (1.0f - z), u - h, h);
      sHimg[lane] = (f16)h;
      __syncthreads();                       // B2: h image ready
    }
  } else {
    // ========= WAVE 1: r producer + hpath stores =========
    uint4 WR[8];
#pragma unroll
    for (int q = 0; q < 8; ++q) WR[q] = odeQ[(0 * 64 + lane) * 8 + q];
#pragma unroll
    for (int q = 0; q < 8; ++q) ANCH4(WR[q]);
    const float xr = gx_b[lane];

    f16* hps = hp16 + (long)b * 64 + lane;
    const long rowstride = (long)B * 64;

    int e_next = 0, s_next = 0x7fffffff, v_cur = 0, v_pipe = 0;
    if (necap > 0) {
      s_next = sStep[0];
      v_cur = sEvt[0];
      v_pipe = (necap > 1) ? sEvt[1] : 0;
    }

#pragma unroll 1
    for (int k = 0; k < n_steps; ++k) {
      if (k == s_next) {
        const bool fire = (v_cur > 0);
        ++e_next;
        if (e_next < necap) {
          s_next = sStep[e_next];
          v_cur = v_pipe;
          v_pipe = (e_next + 1 < necap) ? sEvt[e_next + 1] : 0;
        } else {
          s_next = 0x7fffffff;
          v_cur = 0;
        }
        if (fire) __syncthreads();           // event image ready
      }

      // h_rec = post-event, pre-ODE h (this wave reads it anyway for rh)
      f16 hraw = sHimg[lane];
      *hps = hraw;                           // global store off the master chain
      hps += rowstride;
      float hf = (float)hraw;

      // r gate
      float ar0 = xr, ar1 = 0.f, ar2 = 0.f, ar3 = 0.f;
#pragma unroll
      for (int q = 0; q < 8; ++q) {
        uint4 hp = hq4[q];
        ar0 = dot2(WR[q].x, hp.x, ar0); ar1 = dot2(WR[q].y, hp.y, ar1);
        ar2 = dot2(WR[q].z, hp.z, ar2); ar3 = dot2(WR[q].w, hp.w, ar3);
      }
      float r = sigm((ar0 + ar1) + (ar2 + ar3));
      sRHimg[lane] = (f16)(r * hf);
      __syncthreads();                       // B1: rh image ready
      __syncthreads();                       // B2: h image ready
    }
    *hps = sHimg[lane];                      // h_last
  }
}

// MFMA head (verified R9): out[row] = relu(h[row] @ W1^T + b1) @ W2^T + b2.
__global__ __launch_bounds__(256, 4) void head_mfma_kernel(
    const f16* __restrict__ hp16, const f16* __restrict__ w1P,
    const float* __restrict__ b1, const float* __restrict__ W2,
    const float* __restrict__ b2, float* __restrict__ out, long nrows)
{
  const int wq = threadIdx.x >> 6, lane = threadIdx.x & 63;
  const int col = lane & 15;
  const long rowbase = ((long)blockIdx.x * 4 + wq) * 64;   // 64 rows per wave

  f16x8 Wf[8][2];
#pragma unroll
  for (int t = 0; t < 8; ++t)
#pragma unroll
    for (int kf = 0; kf < 2; ++kf)
      Wf[t][kf] = ((const f16x8*)w1P)[(2 * t + kf) * 64 + lane];

  float b1v[8], w2a[8], w2b[8];
#pragma unroll
  for (int t = 0; t < 8; ++t) {
    b1v[t] = b1[16 * t + col];
    w2a[t] = W2[16 * t + col];
    w2b[t] = W2[128 + 16 * t + col];
  }
  const float b20 = b2[0], b21 = b2[1];

#pragma unroll 1
  for (int g = 0; g < 4; ++g) {
    long row0 = rowbase + g * 16;
    long arow = row0 + col;
    f16x8 aH0 = {0, 0, 0, 0, 0, 0, 0, 0}, aH1 = aH0;
    if (arow < nrows) {
      const f16x8* ap = (const f16x8*)(hp16 + arow * 64);
      aH0 = ap[lane >> 4];
      aH1 = ap[(lane >> 4) + 4];
    }
    float p0[4] = {0.f, 0.f, 0.f, 0.f}, p1[4] = {0.f, 0.f, 0.f, 0.f};
#pragma unroll
    for (int t = 0; t < 8; ++t) {
      f32x4 c = {0.f, 0.f, 0.f, 0.f};
      c = MFMA16(aH0, Wf[t][0], c);
      c = MFMA16(aH1, Wf[t][1], c);
#pragma unroll
      for (int i = 0; i < 4; ++i) {
        float o = fmaxf(c[i] + b1v[t], 0.0f);
        p0[i] = fmaf(o, w2a[t], p0[i]);
        p1[i] = fmaf(o, w2b[t], p1[i]);
      }
    }
#pragma unroll
    for (int off = 1; off < 16; off <<= 1) {
#pragma unroll
      for (int i = 0; i < 4; ++i) {
        p0[i] += __shfl_xor(p0[i], off);
        p1[i] += __shfl_xor(p1[i], off);
      }
    }
    if (col == 0) {
#pragma unroll
      for (int i = 0; i < 4; ++i) {
        long row = row0 + (lane >> 4) * 4 + i;
        if (row < nrows) {
          out[row * 2 + 0] = p0[i] + b20;
          out[row * 2 + 1] = p1[i] + b21;
        }
      }
    }
  }
}

extern "C" void kernel_launch(void* const* d_in, const int* in_sizes, int n_in,
                              void* d_out, int out_size, void* d_ws, size_t ws_size,
                              hipStream_t stream) {
  const float* time_uniq  = (const float*)d_in[0];
  const int*   time_ptr   = (const int*)d_in[1];
  const float* X          = (const float*)d_in[2];
  const int*   sample_ids = (const int*)d_in[3];
  const float* covs       = (const float*)d_in[4];
  const float* cov_W1     = (const float*)d_in[6];
  const float* cov_b1     = (const float*)d_in[7];
  const float* cov_W2     = (const float*)d_in[8];
  const float* cov_b2     = (const float*)d_in[9];
  const float* gb_Wih     = (const float*)d_in[10];
  const float* gb_Whh     = (const float*)d_in[11];
  const float* gb_bih     = (const float*)d_in[12];
  const float* gb_bhh     = (const float*)d_in[13];
  const float* gx_b       = (const float*)d_in[15];
  const float* ghr_W      = (const float*)d_in[16];
  const float* ghz_W      = (const float*)d_in[17];
  const float* ghh_W      = (const float*)d_in[18];
  const float* out_W1     = (const float*)d_in[19];
  const float* out_b1     = (const float*)d_in[20];
  const float* out_W2     = (const float*)d_in[21];
  const float* out_b2     = (const float*)d_in[22];

  int NE   = in_sizes[0];
  int TOT  = in_sizes[3];
  int IN   = in_sizes[2] / TOT;
  int CH   = in_sizes[7];
  int COV  = in_sizes[6] / CH;
  int B    = in_sizes[4] / COV;
  int OUTD = in_sizes[22];
  int n_steps = out_size / (B * OUTD) - 1;
  int OPE  = TOT / NE;

  char* ws = (char*)d_ws;
  int* evtabT = (int*)ws;                       // [B][NEC], transposed
  size_t evbytes = (size_t)B * NEC * sizeof(int);
  size_t off1 = (evbytes + 255) & ~(size_t)255;
  unsigned* odeP = (unsigned*)(ws + off1);
  unsigned* bayP = odeP + 3 * 64 * 32;
  unsigned* wihP = bayP + 3 * 64 * 32;
  size_t off2 = off1 + (((3 * 64 * 32 * 2 + 3 * 64 * 4) * sizeof(unsigned) + 255) & ~(size_t)255);
  f16* w1P = (f16*)(ws + off2);
  size_t off3 = off2 + ((16 * 512 * sizeof(f16) + 255) & ~(size_t)255);
  f16* hp16 = (f16*)(ws + off3);

  hipMemsetAsync(evtabT, 0, evbytes, stream);
  build_evtab_kernel<<<NE, 256, 0, stream>>>(sample_ids, time_ptr, evtabT, B, OPE);
  pack_pairs_kernel<<<24, 256, 0, stream>>>(ghr_W, ghz_W, ghh_W, gb_Whh, gb_Wih,
                                            odeP, bayP, wihP, IN);
  pack_head_kernel<<<16, 64, 0, stream>>>(out_W1, w1P);
  evolve_kernel<<<B, 128, 0, stream>>>(
      time_uniq, X, covs, cov_W1, cov_b1, cov_W2, cov_b2,
      gb_bih, gb_bhh, gx_b, odeP, bayP, wihP,
      evtabT, hp16, B, NE, n_steps, IN, COV);
  long nrows = (long)(n_steps + 1) * B;
  int hb = (int)((nrows + 255) / 256);
  head_mfma_kernel<<<hb, 256, 0, stream>>>(hp16, w1P, out_b1, out_W2, out_b2,
                                           (float*)d_out, nrows);
}